// Round 2
// baseline (2800.103 us; speedup 1.0000x reference)
//
#include <hip/hip_runtime.h>

#define B_   64
#define N_   512
#define R_   256
#define L_   6
#define HID_ 1536

#define TS 64
#define BK 16

__device__ __forceinline__ float silu_f(float x) {
    return x / (1.0f + __expf(-x));
}

// ---------------------------------------------------------------------------
// Generic C[M,Nn] = act(A[M,K] @ W[K,Nn] + bias)   (all row-major, dims % 64)
// block (16,16), tile 64x64, each thread 4x4
// ---------------------------------------------------------------------------
template<int ACT>
__global__ __launch_bounds__(256)
void k_gemm_bias_act(const float* __restrict__ A, const float* __restrict__ W,
                     const float* __restrict__ bias, float* __restrict__ C,
                     int M, int Nn, int K)
{
    __shared__ float As[BK][TS];   // As[k][m]
    __shared__ float Ws[BK][TS];   // Ws[k][n]
    const int tx = threadIdx.x, ty = threadIdx.y;
    const int t  = ty * 16 + tx;
    const int m0 = blockIdx.y * TS, n0 = blockIdx.x * TS;
    const int alm = t >> 2, alk = (t & 3) * 4;    // A loader: row, k4
    const int wr  = t >> 4, wc  = (t & 15) * 4;   // W loader: k-row, col4
    float acc[4][4] = {};
    for (int k0 = 0; k0 < K; k0 += BK) {
        float4 av = *(const float4*)(A + (size_t)(m0 + alm) * K + k0 + alk);
        As[alk + 0][alm] = av.x; As[alk + 1][alm] = av.y;
        As[alk + 2][alm] = av.z; As[alk + 3][alm] = av.w;
        *(float4*)(&Ws[wr][wc]) = *(const float4*)(W + (size_t)(k0 + wr) * Nn + n0 + wc);
        __syncthreads();
        #pragma unroll
        for (int k = 0; k < BK; ++k) {
            float a[4], w[4];
            #pragma unroll
            for (int q = 0; q < 4; ++q) { a[q] = As[k][ty * 4 + q]; w[q] = Ws[k][tx * 4 + q]; }
            #pragma unroll
            for (int ii = 0; ii < 4; ++ii)
                #pragma unroll
                for (int jj = 0; jj < 4; ++jj)
                    acc[ii][jj] = fmaf(a[ii], w[jj], acc[ii][jj]);
        }
        __syncthreads();
    }
    #pragma unroll
    for (int ii = 0; ii < 4; ++ii) {
        const int m = m0 + ty * 4 + ii;
        #pragma unroll
        for (int jj = 0; jj < 4; ++jj) {
            const int n = n0 + tx * 4 + jj;
            float v = acc[ii][jj] + bias[n];
            if (ACT) v = silu_f(v);
            C[(size_t)m * Nn + n] = v;
        }
    }
}

// ---------------------------------------------------------------------------
// Batched S[b,i,j] = sum_r P[b,i,r] * Fn[b,j,r]     (A @ B^T, K = 256)
// ---------------------------------------------------------------------------
__global__ __launch_bounds__(256)
void k_gemm_abt(const float* __restrict__ P, const float* __restrict__ Fn,
                float* __restrict__ S)
{
    __shared__ float As[BK][TS];   // As[k][i]
    __shared__ float Bs[BK][TS];   // Bs[k][j]
    const int tx = threadIdx.x, ty = threadIdx.y;
    const int t  = ty * 16 + tx;
    const int b  = blockIdx.z;
    const int i0 = blockIdx.y * TS, j0 = blockIdx.x * TS;
    const float* Pb = P  + (size_t)b * N_ * R_;
    const float* Fb = Fn + (size_t)b * N_ * R_;
    const int lr = t >> 2, lk = (t & 3) * 4;
    float acc[4][4] = {};
    for (int k0 = 0; k0 < R_; k0 += BK) {
        float4 av = *(const float4*)(Pb + (size_t)(i0 + lr) * R_ + k0 + lk);
        As[lk + 0][lr] = av.x; As[lk + 1][lr] = av.y;
        As[lk + 2][lr] = av.z; As[lk + 3][lr] = av.w;
        float4 bv = *(const float4*)(Fb + (size_t)(j0 + lr) * R_ + k0 + lk);
        Bs[lk + 0][lr] = bv.x; Bs[lk + 1][lr] = bv.y;
        Bs[lk + 2][lr] = bv.z; Bs[lk + 3][lr] = bv.w;
        __syncthreads();
        #pragma unroll
        for (int k = 0; k < BK; ++k) {
            float a[4], w[4];
            #pragma unroll
            for (int q = 0; q < 4; ++q) { a[q] = As[k][ty * 4 + q]; w[q] = Bs[k][tx * 4 + q]; }
            #pragma unroll
            for (int ii = 0; ii < 4; ++ii)
                #pragma unroll
                for (int jj = 0; jj < 4; ++jj)
                    acc[ii][jj] = fmaf(a[ii], w[jj], acc[ii][jj]);
        }
        __syncthreads();
    }
    float* Sb = S + (size_t)b * N_ * N_;
    #pragma unroll
    for (int ii = 0; ii < 4; ++ii)
        #pragma unroll
        for (int jj = 0; jj < 4; ++jj)
            Sb[(size_t)(i0 + ty * 4 + ii) * N_ + j0 + tx * 4 + jj] = acc[ii][jj];
}

// ---------------------------------------------------------------------------
// Masked softmax over axis i (dim=1) of S[b,i,j], in place.
// thread = one column j; reads along i are coalesced across the wave.
// ---------------------------------------------------------------------------
__global__ __launch_bounds__(256)
void k_softmax_col(float* __restrict__ S, const int* __restrict__ adj)
{
    const int b = blockIdx.y;
    const int j = blockIdx.x * 256 + threadIdx.x;
    const size_t base = (size_t)b * N_ * N_ + j;
    float m = -3.0e38f, s = 0.0f;
    for (int i = 0; i < N_; ++i) {
        const size_t idx = base + (size_t)i * N_;
        float v = S[idx];
        v = adj[idx] ? v : -1.0e8f;
        S[idx] = v;                      // store masked value
        const float nm = fmaxf(m, v);
        s = s * __expf(m - nm) + __expf(v - nm);
        m = nm;
    }
    const float inv = 1.0f / s;
    for (int i = 0; i < N_; ++i) {
        const size_t idx = base + (size_t)i * N_;
        S[idx] = __expf(S[idx] - m) * inv;
    }
}

// ---------------------------------------------------------------------------
// Out[b,i,r] = (Fn[b,i,r] + sum_j AS[b,i,j] * Fn[b,j,r]) * F1[b,i,r]
// ---------------------------------------------------------------------------
__global__ __launch_bounds__(256)
void k_gemm_af(const float* __restrict__ AS, const float* __restrict__ Fn,
               const float* __restrict__ F1, float* __restrict__ Out)
{
    __shared__ float As[BK][TS];   // As[kj][i]
    __shared__ float Bs[BK][TS];   // Bs[kj][r]
    const int tx = threadIdx.x, ty = threadIdx.y;
    const int t  = ty * 16 + tx;
    const int b  = blockIdx.z;
    const int i0 = blockIdx.y * TS, r0 = blockIdx.x * TS;
    const float* Ab = AS + (size_t)b * N_ * N_;
    const float* Fb = Fn + (size_t)b * N_ * R_;
    const int ali = t >> 2, alj = (t & 3) * 4;
    const int br  = t >> 4, bc  = (t & 15) * 4;
    float acc[4][4] = {};
    for (int j0 = 0; j0 < N_; j0 += BK) {
        float4 av = *(const float4*)(Ab + (size_t)(i0 + ali) * N_ + j0 + alj);
        As[alj + 0][ali] = av.x; As[alj + 1][ali] = av.y;
        As[alj + 2][ali] = av.z; As[alj + 3][ali] = av.w;
        *(float4*)(&Bs[br][bc]) = *(const float4*)(Fb + (size_t)(j0 + br) * R_ + r0 + bc);
        __syncthreads();
        #pragma unroll
        for (int k = 0; k < BK; ++k) {
            float a[4], w[4];
            #pragma unroll
            for (int q = 0; q < 4; ++q) { a[q] = As[k][ty * 4 + q]; w[q] = Bs[k][tx * 4 + q]; }
            #pragma unroll
            for (int ii = 0; ii < 4; ++ii)
                #pragma unroll
                for (int jj = 0; jj < 4; ++jj)
                    acc[ii][jj] = fmaf(a[ii], w[jj], acc[ii][jj]);
        }
        __syncthreads();
    }
    #pragma unroll
    for (int ii = 0; ii < 4; ++ii)
        #pragma unroll
        for (int jj = 0; jj < 4; ++jj) {
            const size_t idx = (size_t)(b * N_ + i0 + ty * 4 + ii) * R_ + r0 + tx * 4 + jj;
            Out[idx] = (Fn[idx] + acc[ii][jj]) * F1[idx];
        }
}

// ---------------------------------------------------------------------------
// g = silu(X @ Wg + bg); f[b, step*256 + r] += sum_i g[b,i,r]
// ---------------------------------------------------------------------------
__global__ __launch_bounds__(256)
void k_wg_rowsum(const float* __restrict__ X, const float* __restrict__ Wg,
                 const float* __restrict__ bg, float* __restrict__ f, int step)
{
    __shared__ float As[BK][TS];
    __shared__ float Ws[BK][TS];
    __shared__ float red[16][TS];
    const int tx = threadIdx.x, ty = threadIdx.y;
    const int t  = ty * 16 + tx;
    const int m0 = blockIdx.y * TS, n0 = blockIdx.x * TS;
    const int alm = t >> 2, alk = (t & 3) * 4;
    const int wr  = t >> 4, wc  = (t & 15) * 4;
    float acc[4][4] = {};
    for (int k0 = 0; k0 < R_; k0 += BK) {
        float4 av = *(const float4*)(X + (size_t)(m0 + alm) * R_ + k0 + alk);
        As[alk + 0][alm] = av.x; As[alk + 1][alm] = av.y;
        As[alk + 2][alm] = av.z; As[alk + 3][alm] = av.w;
        *(float4*)(&Ws[wr][wc]) = *(const float4*)(Wg + (size_t)(k0 + wr) * R_ + n0 + wc);
        __syncthreads();
        #pragma unroll
        for (int k = 0; k < BK; ++k) {
            float a[4], w[4];
            #pragma unroll
            for (int q = 0; q < 4; ++q) { a[q] = As[k][ty * 4 + q]; w[q] = Ws[k][tx * 4 + q]; }
            #pragma unroll
            for (int ii = 0; ii < 4; ++ii)
                #pragma unroll
                for (int jj = 0; jj < 4; ++jj)
                    acc[ii][jj] = fmaf(a[ii], w[jj], acc[ii][jj]);
        }
        __syncthreads();
    }
    #pragma unroll
    for (int jj = 0; jj < 4; ++jj) {
        const float bb = bg[n0 + tx * 4 + jj];
        float p = 0.0f;
        #pragma unroll
        for (int ii = 0; ii < 4; ++ii)
            p += silu_f(acc[ii][jj] + bb);
        red[ty][tx * 4 + jj] = p;
    }
    __syncthreads();
    if (t < TS) {
        float s2 = 0.0f;
        #pragma unroll
        for (int yy = 0; yy < 16; ++yy) s2 += red[yy][t];
        const int b = blockIdx.y >> 3;   // 8 row-tiles per batch
        atomicAdd(&f[(size_t)b * HID_ + step * R_ + n0 + t], s2);
    }
}

// ---------------------------------------------------------------------------
// f[b,:] /= max(||f[b,:]||, 1e-12)
// ---------------------------------------------------------------------------
__global__ __launch_bounds__(256)
void k_rownorm(float* __restrict__ f)
{
    __shared__ float red[256];
    const int b = blockIdx.x, t = threadIdx.x;
    float ss = 0.0f;
    for (int c = t; c < HID_; c += 256) {
        const float v = f[(size_t)b * HID_ + c];
        ss += v * v;
    }
    red[t] = ss;
    __syncthreads();
    for (int o = 128; o > 0; o >>= 1) {
        if (t < o) red[t] += red[t + o];
        __syncthreads();
    }
    const float inv = 1.0f / fmaxf(sqrtf(red[0]), 1e-12f);
    for (int c = t; c < HID_; c += 256)
        f[(size_t)b * HID_ + c] *= inv;
}

// ---------------------------------------------------------------------------
extern "C" void kernel_launch(void* const* d_in, const int* in_sizes, int n_in,
                              void* d_out, int out_size, void* d_ws, size_t ws_size,
                              hipStream_t stream)
{
    const float* node = (const float*)d_in[0];
    const int*   adj  = (const int*)d_in[1];
    const float* Wv_w = (const float*)d_in[3];  const float* Wv_b = (const float*)d_in[4];
    const float* Ww_w = (const float*)d_in[5];  const float* Ww_b = (const float*)d_in[6];
    const float* Wg_w = (const float*)d_in[7];  const float* Wg_b = (const float*)d_in[8];
    const float* W0 = (const float*)d_in[9];    const float* b0 = (const float*)d_in[10];
    const float* W1 = (const float*)d_in[11];   const float* b1 = (const float*)d_in[12];
    const float* W2 = (const float*)d_in[13];   const float* b2 = (const float*)d_in[14];
    const float* W3 = (const float*)d_in[15];   const float* b3 = (const float*)d_in[16];
    float* out = (float*)d_out;

    float* ws = (float*)d_ws;
    const size_t SZ = (size_t)B_ * N_ * R_;          // 8,388,608 floats
    float* F1   = ws;
    float* Abuf = ws + SZ;
    float* Bbuf = ws + 2 * SZ;
    float* S    = ws + 3 * SZ;                       // 16,777,216 floats
    float* f    = ws + 3 * SZ + (size_t)B_ * N_ * N_;
    float* h0   = f  + (size_t)B_ * HID_;
    float* h1   = h0 + (size_t)B_ * HID_;
    float* h2   = h1 + (size_t)B_ * HID_;

    const dim3 blk(16, 16);
    const dim3 gBig(R_ / TS, (B_ * N_) / TS);        // (4, 512)

    // F1 = silu(node @ Wv + b)
    k_gemm_bias_act<1><<<gBig, blk, 0, stream>>>(node, Wv_w, Wv_b, F1, B_ * N_, R_, 256);
    hipMemsetAsync(f, 0, (size_t)B_ * HID_ * sizeof(float), stream);
    // f_T[0]
    k_wg_rowsum<<<gBig, blk, 0, stream>>>(F1, Wg_w, Wg_b, f, 0);

    const float* X = F1;
    float* Y = Bbuf;
    for (int tstep = 1; tstep < L_; ++tstep) {
        // P = X @ Ww + b   -> Y
        k_gemm_bias_act<0><<<gBig, blk, 0, stream>>>(X, Ww_w, Ww_b, Y, B_ * N_, R_, R_);
        // S = P @ X^T (batched)
        k_gemm_abt<<<dim3(N_ / TS, N_ / TS, B_), blk, 0, stream>>>(Y, X, S);
        // A_S = softmax_i(mask(S))
        k_softmax_col<<<dim3(N_ / 256, B_), 256, 0, stream>>>(S, adj);
        // Fn_new = (X + A_S @ X) * F1  -> Y   (P is dead)
        k_gemm_af<<<dim3(R_ / TS, N_ / TS, B_), blk, 0, stream>>>(S, X, F1, Y);
        // swap
        const float* nx = Y;
        Y = (tstep == 1) ? Abuf : (float*)X;
        X = nx;
        // f_T[tstep]
        k_wg_rowsum<<<gBig, blk, 0, stream>>>(X, Wg_w, Wg_b, f, tstep);
    }

    k_rownorm<<<B_, 256, 0, stream>>>(f);

    // MLP head: 1536 -> 1536 -> 768 -> 128
    k_gemm_bias_act<1><<<dim3(HID_ / TS, 1), blk, 0, stream>>>(f,  W0, b0, h0, B_, HID_, HID_);
    k_gemm_bias_act<1><<<dim3(HID_ / TS, 1), blk, 0, stream>>>(h0, W1, b1, h1, B_, HID_, HID_);
    k_gemm_bias_act<1><<<dim3(768 / TS, 1), blk, 0, stream>>>(h1, W2, b2, h2, B_, 768, HID_);
    k_gemm_bias_act<0><<<dim3(128 / TS, 1), blk, 0, stream>>>(h2, W3, b3, out, B_, 128, 768);
}

// Round 5
// 1399.367 us; speedup vs baseline: 2.0010x; 2.0010x over previous
//
#include <hip/hip_runtime.h>

#define B_   64
#define N_   512
#define R_   256
#define L_   6
#define HID_ 1536

#define BM 128
#define BN 128
#define BK 32
#define LDT 40   // padded LDS stride (u16 elems); 2-way bank alias only = free

typedef __attribute__((ext_vector_type(4))) float f32x4;
typedef __attribute__((ext_vector_type(8))) __bf16 bf16x8;
typedef __attribute__((ext_vector_type(8))) unsigned short u16x8;
typedef unsigned short u16;
typedef unsigned int   u32;

__device__ __forceinline__ float silu_f(float x) { return x / (1.0f + __expf(-x)); }

__device__ __forceinline__ float bf2f(u16 h) {
    u32 u = ((u32)h) << 16;
    return __builtin_bit_cast(float, u);
}
// truncation split: x ~= hi + lo with ~17 effective mantissa bits
__device__ __forceinline__ void split2(float x, u16& h, u16& l) {
    u32 u = __builtin_bit_cast(u32, x);
    h = (u16)(u >> 16);
    float r = x - __builtin_bit_cast(float, u & 0xffff0000u);   // exact
    l = (u16)(__builtin_bit_cast(u32, r) >> 16);
}
__device__ __forceinline__ float join2(u16 h, u16 l) {
    return bf2f(h) + bf2f(l);
}

// ===========================================================================
// Split-GEMM core helper (in k-loop body, after staging + sync):
// acc += Ah*Bh + Al*Bh + Ah*Bl
// ===========================================================================
#define MFMA_TRIPLE(Ash, Asl, Bsh, Bsl)                                         \
    {                                                                           \
        const int k8 = (lane >> 4) * 8, cl = lane & 15;                         \
        bf16x8 bh[4], bl[4];                                                    \
        _Pragma("unroll")                                                       \
        for (int n = 0; n < 4; ++n) {                                           \
            bh[n] = *(const bf16x8*)&Bsh[(wc * 64 + n * 16 + cl) * LDT + k8];   \
            bl[n] = *(const bf16x8*)&Bsl[(wc * 64 + n * 16 + cl) * LDT + k8];   \
        }                                                                       \
        _Pragma("unroll")                                                       \
        for (int m = 0; m < 4; ++m) {                                           \
            bf16x8 ah = *(const bf16x8*)&Ash[(wr * 64 + m * 16 + cl) * LDT + k8]; \
            bf16x8 al = *(const bf16x8*)&Asl[(wr * 64 + m * 16 + cl) * LDT + k8]; \
            _Pragma("unroll")                                                   \
            for (int n = 0; n < 4; ++n) {                                       \
                acc[m][n] = __builtin_amdgcn_mfma_f32_16x16x32_bf16(ah, bh[n], acc[m][n], 0, 0, 0); \
                acc[m][n] = __builtin_amdgcn_mfma_f32_16x16x32_bf16(al, bh[n], acc[m][n], 0, 0, 0); \
                acc[m][n] = __builtin_amdgcn_mfma_f32_16x16x32_bf16(ah, bl[n], acc[m][n], 0, 0, 0); \
            }                                                                   \
        }                                                                       \
    }

// ===========================================================================
// C = act(A @ W + bias), A: fp32 (AFP32=1, on-the-fly split) or hi/lo pair.
// W pre-split as WT[Nn,K] hi/lo. Output written as hi/lo pair.
// ===========================================================================
template<int ACT, int AFP32>
__global__ __launch_bounds__(256)
void k_mf_gemm(const float* __restrict__ Af,
               const u16* __restrict__ Ah, const u16* __restrict__ Al,
               const u16* __restrict__ WTh, const u16* __restrict__ WTl,
               const float* __restrict__ bias,
               u16* __restrict__ Ch, u16* __restrict__ Cl,
               int M, int Nn, int K)
{
    __shared__ u16 Ash[BM * LDT], Asl[BM * LDT];
    __shared__ u16 Bsh[BN * LDT], Bsl[BN * LDT];
    const int t = threadIdx.x, lane = t & 63, w = t >> 6;
    const int wr = w >> 1, wc = w & 1;
    const int m0 = blockIdx.y * BM, n0 = blockIdx.x * BN;
    const int sr = t >> 1, sc = (t & 1) * 16;
    f32x4 acc[4][4] = {};
    for (int k0 = 0; k0 < K; k0 += BK) {
        if (AFP32) {
            const float* ga = Af + (size_t)(m0 + sr) * K + k0 + sc;
            u16x8 vh0, vl0, vh1, vl1;
            #pragma unroll
            for (int p = 0; p < 2; ++p) {
                const float4 a = *(const float4*)(ga + p * 8);
                const float4 b = *(const float4*)(ga + p * 8 + 4);
                u16 h, l;
                split2(a.x, h, l); (p ? vh1 : vh0)[0] = h; (p ? vl1 : vl0)[0] = l;
                split2(a.y, h, l); (p ? vh1 : vh0)[1] = h; (p ? vl1 : vl0)[1] = l;
                split2(a.z, h, l); (p ? vh1 : vh0)[2] = h; (p ? vl1 : vl0)[2] = l;
                split2(a.w, h, l); (p ? vh1 : vh0)[3] = h; (p ? vl1 : vl0)[3] = l;
                split2(b.x, h, l); (p ? vh1 : vh0)[4] = h; (p ? vl1 : vl0)[4] = l;
                split2(b.y, h, l); (p ? vh1 : vh0)[5] = h; (p ? vl1 : vl0)[5] = l;
                split2(b.z, h, l); (p ? vh1 : vh0)[6] = h; (p ? vl1 : vl0)[6] = l;
                split2(b.w, h, l); (p ? vh1 : vh0)[7] = h; (p ? vl1 : vl0)[7] = l;
            }
            *(u16x8*)&Ash[sr * LDT + sc]     = vh0;
            *(u16x8*)&Ash[sr * LDT + sc + 8] = vh1;
            *(u16x8*)&Asl[sr * LDT + sc]     = vl0;
            *(u16x8*)&Asl[sr * LDT + sc + 8] = vl1;
        } else {
            const u16* gah = Ah + (size_t)(m0 + sr) * K + k0 + sc;
            const u16* gal = Al + (size_t)(m0 + sr) * K + k0 + sc;
            *(u16x8*)&Ash[sr * LDT + sc]     = *(const u16x8*)(gah);
            *(u16x8*)&Ash[sr * LDT + sc + 8] = *(const u16x8*)(gah + 8);
            *(u16x8*)&Asl[sr * LDT + sc]     = *(const u16x8*)(gal);
            *(u16x8*)&Asl[sr * LDT + sc + 8] = *(const u16x8*)(gal + 8);
        }
        const u16* gbh = WTh + (size_t)(n0 + sr) * K + k0 + sc;
        const u16* gbl = WTl + (size_t)(n0 + sr) * K + k0 + sc;
        *(u16x8*)&Bsh[sr * LDT + sc]     = *(const u16x8*)(gbh);
        *(u16x8*)&Bsh[sr * LDT + sc + 8] = *(const u16x8*)(gbh + 8);
        *(u16x8*)&Bsl[sr * LDT + sc]     = *(const u16x8*)(gbl);
        *(u16x8*)&Bsl[sr * LDT + sc + 8] = *(const u16x8*)(gbl + 8);
        __syncthreads();
        MFMA_TRIPLE(Ash, Asl, Bsh, Bsl)
        __syncthreads();
    }
    const int cl = lane & 15, rh = lane >> 4;
    #pragma unroll
    for (int m = 0; m < 4; ++m)
        #pragma unroll
        for (int n = 0; n < 4; ++n) {
            const int col = n0 + wc * 64 + n * 16 + cl;
            const float bb = bias[col];
            #pragma unroll
            for (int q = 0; q < 4; ++q) {
                const int row = m0 + wr * 64 + m * 16 + rh * 4 + q;
                float v = acc[m][n][q] + bb;
                if (ACT) v = silu_f(v);
                const size_t idx = (size_t)row * Nn + col;
                split2(v, Ch[idx], Cl[idx]);
            }
        }
}

// ===========================================================================
// S[b,i,j] = sum_r P[b,i,r]*Fn[b,j,r], masked -> fp32
// ===========================================================================
__global__ __launch_bounds__(256)
void k_mf_abt(const u16* __restrict__ Ph, const u16* __restrict__ Pl,
              const u16* __restrict__ Fh, const u16* __restrict__ Fl,
              const int* __restrict__ adj, float* __restrict__ S)
{
    __shared__ u16 Ash[BM * LDT], Asl[BM * LDT];
    __shared__ u16 Bsh[BN * LDT], Bsl[BN * LDT];
    const int t = threadIdx.x, lane = t & 63, w = t >> 6;
    const int wr = w >> 1, wc = w & 1;
    const int b = blockIdx.z;
    const int i0 = blockIdx.y * BM, j0 = blockIdx.x * BN;
    const size_t boff = (size_t)b * N_ * R_;
    const int sr = t >> 1, sc = (t & 1) * 16;
    f32x4 acc[4][4] = {};
    for (int k0 = 0; k0 < R_; k0 += BK) {
        const u16* gah = Ph + boff + (size_t)(i0 + sr) * R_ + k0 + sc;
        const u16* gal = Pl + boff + (size_t)(i0 + sr) * R_ + k0 + sc;
        const u16* gbh = Fh + boff + (size_t)(j0 + sr) * R_ + k0 + sc;
        const u16* gbl = Fl + boff + (size_t)(j0 + sr) * R_ + k0 + sc;
        *(u16x8*)&Ash[sr * LDT + sc]     = *(const u16x8*)(gah);
        *(u16x8*)&Ash[sr * LDT + sc + 8] = *(const u16x8*)(gah + 8);
        *(u16x8*)&Asl[sr * LDT + sc]     = *(const u16x8*)(gal);
        *(u16x8*)&Asl[sr * LDT + sc + 8] = *(const u16x8*)(gal + 8);
        *(u16x8*)&Bsh[sr * LDT + sc]     = *(const u16x8*)(gbh);
        *(u16x8*)&Bsh[sr * LDT + sc + 8] = *(const u16x8*)(gbh + 8);
        *(u16x8*)&Bsl[sr * LDT + sc]     = *(const u16x8*)(gbl);
        *(u16x8*)&Bsl[sr * LDT + sc + 8] = *(const u16x8*)(gbl + 8);
        __syncthreads();
        MFMA_TRIPLE(Ash, Asl, Bsh, Bsl)
        __syncthreads();
    }
    const int cl = lane & 15, rh = lane >> 4;
    const int*  adjb = adj + (size_t)b * N_ * N_;
    float*      Sb   = S   + (size_t)b * N_ * N_;
    #pragma unroll
    for (int m = 0; m < 4; ++m)
        #pragma unroll
        for (int n = 0; n < 4; ++n)
            #pragma unroll
            for (int q = 0; q < 4; ++q) {
                const int row = i0 + wr * 64 + m * 16 + rh * 4 + q;
                const int col = j0 + wc * 64 + n * 16 + cl;
                const size_t idx = (size_t)row * N_ + col;
                Sb[idx] = adjb[idx] ? acc[m][n][q] : -1.0e8f;
            }
}

// ===========================================================================
// Column stats over axis i: m_j, invD_j  (fp32)
// ===========================================================================
__global__ __launch_bounds__(256)
void k_colstats(const float* __restrict__ S, float* __restrict__ mj,
                float* __restrict__ invD)
{
    __shared__ float lm[4][64], ls[4][64];
    const int t = threadIdx.x;
    const int q = t >> 6, c = t & 63;
    const int b = blockIdx.x >> 3;
    const int j = (blockIdx.x & 7) * 64 + c;
    const float* Sb = S + (size_t)b * N_ * N_ + j;
    float m = -3.0e38f, s = 0.0f;
    for (int i = q * 128; i < q * 128 + 128; ++i) {
        const float v = Sb[(size_t)i * N_];
        const float nm = fmaxf(m, v);
        s = s * __expf(m - nm) + __expf(v - nm);
        m = nm;
    }
    lm[q][c] = m; ls[q][c] = s;
    __syncthreads();
    if (q == 0) {
        float M = lm[0][c];
        #pragma unroll
        for (int k = 1; k < 4; ++k) M = fmaxf(M, lm[k][c]);
        float D = 0.0f;
        #pragma unroll
        for (int k = 0; k < 4; ++k) D += ls[k][c] * __expf(lm[k][c] - M);
        mj[(size_t)b * N_ + j]   = M;
        invD[(size_t)b * N_ + j] = 1.0f / D;
    }
}

// ===========================================================================
// Out = (Fn + softmax(S) @ Fn) * F1 ; A staged from fp32 S (exp-normalized,
// split hi/lo), B = FT hi/lo; output split hi/lo
// ===========================================================================
__global__ __launch_bounds__(256)
void k_mf_af(const float* __restrict__ S, const float* __restrict__ mj,
             const float* __restrict__ invD,
             const u16* __restrict__ FTh, const u16* __restrict__ FTl,
             const u16* __restrict__ Fh, const u16* __restrict__ Fl,
             const u16* __restrict__ F1h, const u16* __restrict__ F1l,
             u16* __restrict__ Oh, u16* __restrict__ Ol)
{
    __shared__ u16 Ash[BM * LDT], Asl[BM * LDT];
    __shared__ u16 Bsh[BN * LDT], Bsl[BN * LDT];
    const int t = threadIdx.x, lane = t & 63, w = t >> 6;
    const int wr = w >> 1, wc = w & 1;
    const int b = blockIdx.z;
    const int i0 = blockIdx.y * BM, r0 = blockIdx.x * BN;
    const float* Sb  = S    + (size_t)b * N_ * N_;
    const float* mb  = mj   + (size_t)b * N_;
    const float* db  = invD + (size_t)b * N_;
    const size_t tboff = (size_t)b * R_ * N_;
    const int sr = t >> 1, sc = (t & 1) * 16;
    f32x4 acc[4][4] = {};
    for (int k0 = 0; k0 < N_; k0 += BK) {          // k = j
        const float* gs = Sb + (size_t)(i0 + sr) * N_ + k0 + sc;
        const float* gm = mb + k0 + sc;
        const float* gd = db + k0 + sc;
        #pragma unroll
        for (int h = 0; h < 2; ++h) {
            u16x8 vh, vl;
            #pragma unroll
            for (int p4 = 0; p4 < 2; ++p4) {
                const float4 sv = *(const float4*)(gs + h * 8 + p4 * 4);
                const float4 mv = *(const float4*)(gm + h * 8 + p4 * 4);
                const float4 dv = *(const float4*)(gd + h * 8 + p4 * 4);
                u16 th, tl;
                split2(__expf(sv.x - mv.x) * dv.x, th, tl); vh[p4 * 4 + 0] = th; vl[p4 * 4 + 0] = tl;
                split2(__expf(sv.y - mv.y) * dv.y, th, tl); vh[p4 * 4 + 1] = th; vl[p4 * 4 + 1] = tl;
                split2(__expf(sv.z - mv.z) * dv.z, th, tl); vh[p4 * 4 + 2] = th; vl[p4 * 4 + 2] = tl;
                split2(__expf(sv.w - mv.w) * dv.w, th, tl); vh[p4 * 4 + 3] = th; vl[p4 * 4 + 3] = tl;
            }
            *(u16x8*)&Ash[sr * LDT + sc + h * 8] = vh;
            *(u16x8*)&Asl[sr * LDT + sc + h * 8] = vl;
        }
        const u16* gbh = FTh + tboff + (size_t)(r0 + sr) * N_ + k0 + sc;
        const u16* gbl = FTl + tboff + (size_t)(r0 + sr) * N_ + k0 + sc;
        *(u16x8*)&Bsh[sr * LDT + sc]     = *(const u16x8*)(gbh);
        *(u16x8*)&Bsh[sr * LDT + sc + 8] = *(const u16x8*)(gbh + 8);
        *(u16x8*)&Bsl[sr * LDT + sc]     = *(const u16x8*)(gbl);
        *(u16x8*)&Bsl[sr * LDT + sc + 8] = *(const u16x8*)(gbl + 8);
        __syncthreads();
        MFMA_TRIPLE(Ash, Asl, Bsh, Bsl)
        __syncthreads();
    }
    const int cl = lane & 15, rh = lane >> 4;
    #pragma unroll
    for (int m = 0; m < 4; ++m)
        #pragma unroll
        for (int n = 0; n < 4; ++n)
            #pragma unroll
            for (int q = 0; q < 4; ++q) {
                const int row = i0 + wr * 64 + m * 16 + rh * 4 + q;
                const int col = r0 + wc * 64 + n * 16 + cl;
                const size_t idx = ((size_t)b * N_ + row) * R_ + col;
                const float fn = join2(Fh[idx], Fl[idx]);
                const float f1 = join2(F1h[idx], F1l[idx]);
                split2((fn + acc[m][n][q]) * f1, Oh[idx], Ol[idx]);
            }
}

// ===========================================================================
// g = silu(X @ Wg + bg); f[b, step*R + n] += sum_rows g
// ===========================================================================
__global__ __launch_bounds__(256)
void k_mf_wg(const u16* __restrict__ Xh, const u16* __restrict__ Xl,
             const u16* __restrict__ WgTh, const u16* __restrict__ WgTl,
             const float* __restrict__ bg, float* __restrict__ f, int step)
{
    __shared__ u16 Ash[BM * LDT], Asl[BM * LDT];
    __shared__ u16 Bsh[BN * LDT], Bsl[BN * LDT];
    const int t = threadIdx.x, lane = t & 63, w = t >> 6;
    const int wr = w >> 1, wc = w & 1;
    const int m0 = blockIdx.y * BM, n0 = blockIdx.x * BN;
    const int sr = t >> 1, sc = (t & 1) * 16;
    f32x4 acc[4][4] = {};
    for (int k0 = 0; k0 < R_; k0 += BK) {
        const u16* gah = Xh + (size_t)(m0 + sr) * R_ + k0 + sc;
        const u16* gal = Xl + (size_t)(m0 + sr) * R_ + k0 + sc;
        const u16* gbh = WgTh + (size_t)(n0 + sr) * R_ + k0 + sc;
        const u16* gbl = WgTl + (size_t)(n0 + sr) * R_ + k0 + sc;
        *(u16x8*)&Ash[sr * LDT + sc]     = *(const u16x8*)(gah);
        *(u16x8*)&Ash[sr * LDT + sc + 8] = *(const u16x8*)(gah + 8);
        *(u16x8*)&Asl[sr * LDT + sc]     = *(const u16x8*)(gal);
        *(u16x8*)&Asl[sr * LDT + sc + 8] = *(const u16x8*)(gal + 8);
        *(u16x8*)&Bsh[sr * LDT + sc]     = *(const u16x8*)(gbh);
        *(u16x8*)&Bsh[sr * LDT + sc + 8] = *(const u16x8*)(gbh + 8);
        *(u16x8*)&Bsl[sr * LDT + sc]     = *(const u16x8*)(gbl);
        *(u16x8*)&Bsl[sr * LDT + sc + 8] = *(const u16x8*)(gbl + 8);
        __syncthreads();
        MFMA_TRIPLE(Ash, Asl, Bsh, Bsl)
        __syncthreads();
    }
    const int cl = lane & 15, rh = lane >> 4;
    const int bb = blockIdx.y >> 2;              // 4 row-tiles of 128 per batch
    #pragma unroll
    for (int n = 0; n < 4; ++n) {
        const int col = n0 + wc * 64 + n * 16 + cl;
        const float bias = bg[col];
        float s = 0.0f;
        #pragma unroll
        for (int m = 0; m < 4; ++m)
            #pragma unroll
            for (int q = 0; q < 4; ++q)
                s += silu_f(acc[m][n][q] + bias);
        s += __shfl_xor(s, 16);
        s += __shfl_xor(s, 32);
        if (rh == 0)
            atomicAdd(&f[(size_t)bb * HID_ + step * R_ + col], s);
    }
}

// ===========================================================================
// u16 plane transpose: FT[b,r,i] = Fn[b,i,r]
// ===========================================================================
#define TLD 72
__global__ __launch_bounds__(256)
void k_transpose_bf(const u16* __restrict__ Fn, u16* __restrict__ FT)
{
    __shared__ u16 tile[64 * TLD];
    const int b = blockIdx.z;
    const int i0 = blockIdx.y * 64;
    const int r0 = blockIdx.x * 64;
    const u16* src = Fn + ((size_t)b * N_ + i0) * R_ + r0;
    u16*       dst = FT + ((size_t)b * R_ + r0) * N_ + i0;
    const int t = threadIdx.x;
    const int rr = t >> 2, cc = (t & 3) * 16;
    *(u16x8*)&tile[rr * TLD + cc]     = *(const u16x8*)(src + (size_t)rr * R_ + cc);
    *(u16x8*)&tile[rr * TLD + cc + 8] = *(const u16x8*)(src + (size_t)rr * R_ + cc + 8);
    __syncthreads();
    const int ro = t >> 2, co = (t & 3) * 16;
    u16x8 v0, v1;
    #pragma unroll
    for (int q = 0; q < 8; ++q) v0[q] = tile[(co + q) * TLD + ro];
    #pragma unroll
    for (int q = 0; q < 8; ++q) v1[q] = tile[(co + 8 + q) * TLD + ro];
    *(u16x8*)(dst + (size_t)ro * N_ + co)     = v0;
    *(u16x8*)(dst + (size_t)ro * N_ + co + 8) = v1;
}

// WT[n,k] hi/lo = split(W[k,n])
__global__ __launch_bounds__(256)
void k_cvt_wT(const float* __restrict__ Win, u16* __restrict__ WTh,
              u16* __restrict__ WTl, int K, int Nn)
{
    const int idx = blockIdx.x * 256 + threadIdx.x;
    if (idx < K * Nn) {
        const int n = idx / K, k = idx % K;
        split2(Win[(size_t)k * Nn + n], WTh[idx], WTl[idx]);
    }
}

// ===========================================================================
// fp32 tile GEMM for the tiny MLP head
// ===========================================================================
#define TS 64
#define FBK 16
template<int ACT>
__global__ __launch_bounds__(256)
void k_gemm_bias_act(const float* __restrict__ A, const float* __restrict__ W,
                     const float* __restrict__ bias, float* __restrict__ C,
                     int M, int Nn, int K)
{
    __shared__ float As[FBK][TS];
    __shared__ float Ws[FBK][TS];
    const int tx = threadIdx.x, ty = threadIdx.y;
    const int t  = ty * 16 + tx;
    const int m0 = blockIdx.y * TS, n0 = blockIdx.x * TS;
    const int alm = t >> 2, alk = (t & 3) * 4;
    const int wr  = t >> 4, wc  = (t & 15) * 4;
    float acc[4][4] = {};
    for (int k0 = 0; k0 < K; k0 += FBK) {
        float4 av = *(const float4*)(A + (size_t)(m0 + alm) * K + k0 + alk);
        As[alk + 0][alm] = av.x; As[alk + 1][alm] = av.y;
        As[alk + 2][alm] = av.z; As[alk + 3][alm] = av.w;
        *(float4*)(&Ws[wr][wc]) = *(const float4*)(W + (size_t)(k0 + wr) * Nn + n0 + wc);
        __syncthreads();
        #pragma unroll
        for (int k = 0; k < FBK; ++k) {
            float a[4], w2[4];
            #pragma unroll
            for (int q = 0; q < 4; ++q) { a[q] = As[k][ty * 4 + q]; w2[q] = Ws[k][tx * 4 + q]; }
            #pragma unroll
            for (int ii = 0; ii < 4; ++ii)
                #pragma unroll
                for (int jj = 0; jj < 4; ++jj)
                    acc[ii][jj] = fmaf(a[ii], w2[jj], acc[ii][jj]);
        }
        __syncthreads();
    }
    #pragma unroll
    for (int ii = 0; ii < 4; ++ii) {
        const int m = m0 + ty * 4 + ii;
        #pragma unroll
        for (int jj = 0; jj < 4; ++jj) {
            const int n = n0 + tx * 4 + jj;
            float v = acc[ii][jj] + bias[n];
            if (ACT) v = silu_f(v);
            C[(size_t)m * Nn + n] = v;
        }
    }
}

__global__ __launch_bounds__(256)
void k_rownorm(float* __restrict__ f)
{
    __shared__ float red[256];
    const int b = blockIdx.x, t = threadIdx.x;
    float ss = 0.0f;
    for (int c = t; c < HID_; c += 256) {
        const float v = f[(size_t)b * HID_ + c];
        ss += v * v;
    }
    red[t] = ss;
    __syncthreads();
    for (int o = 128; o > 0; o >>= 1) {
        if (t < o) red[t] += red[t + o];
        __syncthreads();
    }
    const float inv = 1.0f / fmaxf(sqrtf(red[0]), 1e-12f);
    for (int c = t; c < HID_; c += 256)
        f[(size_t)b * HID_ + c] *= inv;
}

// ===========================================================================
extern "C" void kernel_launch(void* const* d_in, const int* in_sizes, int n_in,
                              void* d_out, int out_size, void* d_ws, size_t ws_size,
                              hipStream_t stream)
{
    const float* node = (const float*)d_in[0];
    const int*   adj  = (const int*)d_in[1];
    const float* Wv_w = (const float*)d_in[3];  const float* Wv_b = (const float*)d_in[4];
    const float* Ww_w = (const float*)d_in[5];  const float* Ww_b = (const float*)d_in[6];
    const float* Wg_w = (const float*)d_in[7];  const float* Wg_b = (const float*)d_in[8];
    const float* W0 = (const float*)d_in[9];    const float* b0 = (const float*)d_in[10];
    const float* W1 = (const float*)d_in[11];   const float* b1 = (const float*)d_in[12];
    const float* W2 = (const float*)d_in[13];   const float* b2 = (const float*)d_in[14];
    const float* W3 = (const float*)d_in[15];   const float* b3 = (const float*)d_in[16];
    float* out = (float*)d_out;

    float* ws = (float*)d_ws;
    const size_t SZ = (size_t)B_ * N_ * R_;              // 8,388,608 elems
    float* S     = ws;                                   // B*N*N fp32
    float* h0    = ws;                                   // alias S (post-loop)
    float* h1    = ws + 98304;
    float* h2    = ws + 196608;
    float* mj    = ws + (size_t)B_ * N_ * N_;            // 32768
    float* invD  = mj + 32768;
    float* f     = invD + 32768;                         // 98304
    u16* u0   = (u16*)(f + 98304);
    u16* F1h  = u0;            u16* F1l  = F1h + SZ;
    u16* X1h  = F1l + SZ;      u16* X1l  = X1h + SZ;
    u16* X2h  = X1l + SZ;      u16* X2l  = X2h + SZ;
    u16* XTh  = X2l + SZ;      u16* XTl  = XTh + SZ;
    u16* Ph   = XTl + SZ;      u16* Pl   = Ph + SZ;
    u16* WvTh = Pl + SZ;       u16* WvTl = WvTh + 65536;
    u16* WwTh = WvTl + 65536;  u16* WwTl = WwTh + 65536;
    u16* WgTh = WwTl + 65536;  u16* WgTl = WgTh + 65536;

    // --- weight splits (once per launch) ---
    k_cvt_wT<<<256, 256, 0, stream>>>(Wv_w, WvTh, WvTl, 256, 256);
    k_cvt_wT<<<256, 256, 0, stream>>>(Ww_w, WwTh, WwTl, 256, 256);
    k_cvt_wT<<<256, 256, 0, stream>>>(Wg_w, WgTh, WgTl, 256, 256);
    (void)hipMemsetAsync(f, 0, 98304 * sizeof(float), stream);

    // --- F1 = silu(node @ Wv + b)  (A = fp32 node, on-the-fly split) ---
    k_mf_gemm<1, 1><<<dim3(2, 256), 256, 0, stream>>>(
        node, nullptr, nullptr, WvTh, WvTl, Wv_b, F1h, F1l, B_ * N_, R_, 256);
    k_mf_wg<<<dim3(2, 256), 256, 0, stream>>>(F1h, F1l, WgTh, WgTl, Wg_b, f, 0);
    k_transpose_bf<<<dim3(4, 8, 64), 256, 0, stream>>>(F1h, XTh);
    k_transpose_bf<<<dim3(4, 8, 64), 256, 0, stream>>>(F1l, XTl);

    const u16 *Xh = F1h, *Xl = F1l;
    u16 *Yh = X1h, *Yl = X1l;
    for (int step = 1; step < L_; ++step) {
        k_mf_gemm<0, 0><<<dim3(2, 256), 256, 0, stream>>>(
            nullptr, Xh, Xl, WwTh, WwTl, Ww_b, Ph, Pl, B_ * N_, R_, 256);
        k_mf_abt<<<dim3(4, 4, 64), 256, 0, stream>>>(Ph, Pl, Xh, Xl, adj, S);
        k_colstats<<<512, 256, 0, stream>>>(S, mj, invD);
        k_mf_af<<<dim3(2, 4, 64), 256, 0, stream>>>(
            S, mj, invD, XTh, XTl, Xh, Xl, F1h, F1l, Yh, Yl);
        k_mf_wg<<<dim3(2, 256), 256, 0, stream>>>(Yh, Yl, WgTh, WgTl, Wg_b, f, step);
        if (step < L_ - 1) {
            k_transpose_bf<<<dim3(4, 8, 64), 256, 0, stream>>>(Yh, XTh);
            k_transpose_bf<<<dim3(4, 8, 64), 256, 0, stream>>>(Yl, XTl);
        }
        const u16 *nxh = Yh, *nxl = Yl;
        if (step == 1) { Yh = X2h; Yl = X2l; }
        else           { Yh = (u16*)Xh; Yl = (u16*)Xl; }
        Xh = nxh; Xl = nxl;
    }

    k_rownorm<<<B_, 256, 0, stream>>>(f);

    // --- MLP head (fp32): 1536 -> 1536 -> 768 -> 128 ---
    const dim3 fblk(16, 16);
    k_gemm_bias_act<1><<<dim3(24, 1), fblk, 0, stream>>>(f,  W0, b0, h0, B_, HID_, HID_);
    k_gemm_bias_act<1><<<dim3(24, 1), fblk, 0, stream>>>(h0, W1, b1, h1, B_, HID_, HID_);
    k_gemm_bias_act<1><<<dim3(12, 1), fblk, 0, stream>>>(h1, W2, b2, h2, B_, 768, HID_);
    k_gemm_bias_act<0><<<dim3(2, 1),  fblk, 0, stream>>>(h2, W3, b3, out, B_, 128, 768);
}

// Round 6
// 1099.851 us; speedup vs baseline: 2.5459x; 1.2723x over previous
//
#include <hip/hip_runtime.h>

#define B_   64
#define N_   512
#define R_   256
#define L_   6
#define HID_ 1536

#define BM 128
#define BN 128
#define BK 32
#define LDT 40   // padded LDS stride (u16 elems); 2-way bank alias only = free

typedef __attribute__((ext_vector_type(4))) float f32x4;
typedef __attribute__((ext_vector_type(8))) __bf16 bf16x8;
typedef __attribute__((ext_vector_type(8))) unsigned short u16x8;
typedef unsigned short u16;
typedef unsigned int   u32;

__device__ __forceinline__ float silu_f(float x) { return x / (1.0f + __expf(-x)); }

__device__ __forceinline__ float bf2f(u16 h) {
    u32 u = ((u32)h) << 16;
    return __builtin_bit_cast(float, u);
}
// truncation split: x ~= hi + lo with ~17 effective mantissa bits
__device__ __forceinline__ void split2(float x, u16& h, u16& l) {
    u32 u = __builtin_bit_cast(u32, x);
    h = (u16)(u >> 16);
    float r = x - __builtin_bit_cast(float, u & 0xffff0000u);   // exact
    l = (u16)(__builtin_bit_cast(u32, r) >> 16);
}
__device__ __forceinline__ float join2(u16 h, u16 l) {
    return bf2f(h) + bf2f(l);
}

// ===========================================================================
// Split-GEMM core helper: acc += Ah*Bh + Al*Bh + Ah*Bl
// ===========================================================================
#define MFMA_TRIPLE(Ash, Asl, Bsh, Bsl)                                         \
    {                                                                           \
        const int k8 = (lane >> 4) * 8, cl = lane & 15;                         \
        bf16x8 bh[4], bl[4];                                                    \
        _Pragma("unroll")                                                       \
        for (int n = 0; n < 4; ++n) {                                           \
            bh[n] = *(const bf16x8*)&Bsh[(wc * 64 + n * 16 + cl) * LDT + k8];   \
            bl[n] = *(const bf16x8*)&Bsl[(wc * 64 + n * 16 + cl) * LDT + k8];   \
        }                                                                       \
        _Pragma("unroll")                                                       \
        for (int m = 0; m < 4; ++m) {                                           \
            bf16x8 ah = *(const bf16x8*)&Ash[(wr * 64 + m * 16 + cl) * LDT + k8]; \
            bf16x8 al = *(const bf16x8*)&Asl[(wr * 64 + m * 16 + cl) * LDT + k8]; \
            _Pragma("unroll")                                                   \
            for (int n = 0; n < 4; ++n) {                                       \
                acc[m][n] = __builtin_amdgcn_mfma_f32_16x16x32_bf16(ah, bh[n], acc[m][n], 0, 0, 0); \
                acc[m][n] = __builtin_amdgcn_mfma_f32_16x16x32_bf16(al, bh[n], acc[m][n], 0, 0, 0); \
                acc[m][n] = __builtin_amdgcn_mfma_f32_16x16x32_bf16(ah, bl[n], acc[m][n], 0, 0, 0); \
            }                                                                   \
        }                                                                       \
    }

// ===========================================================================
// C = act(A @ W + bias), A: fp32 (AFP32=1, on-the-fly split) or hi/lo pair.
// W pre-split as WT[Nn,K] hi/lo. Output written as hi/lo pair.
// ===========================================================================
template<int ACT, int AFP32>
__global__ __launch_bounds__(256)
void k_mf_gemm(const float* __restrict__ Af,
               const u16* __restrict__ Ah, const u16* __restrict__ Al,
               const u16* __restrict__ WTh, const u16* __restrict__ WTl,
               const float* __restrict__ bias,
               u16* __restrict__ Ch, u16* __restrict__ Cl,
               int M, int Nn, int K)
{
    __shared__ u16 Ash[BM * LDT], Asl[BM * LDT];
    __shared__ u16 Bsh[BN * LDT], Bsl[BN * LDT];
    const int t = threadIdx.x, lane = t & 63, w = t >> 6;
    const int wr = w >> 1, wc = w & 1;
    const int m0 = blockIdx.y * BM, n0 = blockIdx.x * BN;
    const int sr = t >> 1, sc = (t & 1) * 16;
    f32x4 acc[4][4] = {};
    for (int k0 = 0; k0 < K; k0 += BK) {
        if (AFP32) {
            const float* ga = Af + (size_t)(m0 + sr) * K + k0 + sc;
            u16x8 vh0, vl0, vh1, vl1;
            #pragma unroll
            for (int p = 0; p < 2; ++p) {
                const float4 a = *(const float4*)(ga + p * 8);
                const float4 b = *(const float4*)(ga + p * 8 + 4);
                u16 h, l;
                split2(a.x, h, l); (p ? vh1 : vh0)[0] = h; (p ? vl1 : vl0)[0] = l;
                split2(a.y, h, l); (p ? vh1 : vh0)[1] = h; (p ? vl1 : vl0)[1] = l;
                split2(a.z, h, l); (p ? vh1 : vh0)[2] = h; (p ? vl1 : vl0)[2] = l;
                split2(a.w, h, l); (p ? vh1 : vh0)[3] = h; (p ? vl1 : vl0)[3] = l;
                split2(b.x, h, l); (p ? vh1 : vh0)[4] = h; (p ? vl1 : vl0)[4] = l;
                split2(b.y, h, l); (p ? vh1 : vh0)[5] = h; (p ? vl1 : vl0)[5] = l;
                split2(b.z, h, l); (p ? vh1 : vh0)[6] = h; (p ? vl1 : vl0)[6] = l;
                split2(b.w, h, l); (p ? vh1 : vh0)[7] = h; (p ? vl1 : vl0)[7] = l;
            }
            *(u16x8*)&Ash[sr * LDT + sc]     = vh0;
            *(u16x8*)&Ash[sr * LDT + sc + 8] = vh1;
            *(u16x8*)&Asl[sr * LDT + sc]     = vl0;
            *(u16x8*)&Asl[sr * LDT + sc + 8] = vl1;
        } else {
            const u16* gah = Ah + (size_t)(m0 + sr) * K + k0 + sc;
            const u16* gal = Al + (size_t)(m0 + sr) * K + k0 + sc;
            *(u16x8*)&Ash[sr * LDT + sc]     = *(const u16x8*)(gah);
            *(u16x8*)&Ash[sr * LDT + sc + 8] = *(const u16x8*)(gah + 8);
            *(u16x8*)&Asl[sr * LDT + sc]     = *(const u16x8*)(gal);
            *(u16x8*)&Asl[sr * LDT + sc + 8] = *(const u16x8*)(gal + 8);
        }
        const u16* gbh = WTh + (size_t)(n0 + sr) * K + k0 + sc;
        const u16* gbl = WTl + (size_t)(n0 + sr) * K + k0 + sc;
        *(u16x8*)&Bsh[sr * LDT + sc]     = *(const u16x8*)(gbh);
        *(u16x8*)&Bsh[sr * LDT + sc + 8] = *(const u16x8*)(gbh + 8);
        *(u16x8*)&Bsl[sr * LDT + sc]     = *(const u16x8*)(gbl);
        *(u16x8*)&Bsl[sr * LDT + sc + 8] = *(const u16x8*)(gbl + 8);
        __syncthreads();
        MFMA_TRIPLE(Ash, Asl, Bsh, Bsl)
        __syncthreads();
    }
    const int cl = lane & 15, rh = lane >> 4;
    #pragma unroll
    for (int m = 0; m < 4; ++m)
        #pragma unroll
        for (int n = 0; n < 4; ++n) {
            const int col = n0 + wc * 64 + n * 16 + cl;
            const float bb = bias[col];
            #pragma unroll
            for (int q = 0; q < 4; ++q) {
                const int row = m0 + wr * 64 + m * 16 + rh * 4 + q;
                float v = acc[m][n][q] + bb;
                if (ACT) v = silu_f(v);
                const size_t idx = (size_t)row * Nn + col;
                split2(v, Ch[idx], Cl[idx]);
            }
        }
}

// ===========================================================================
// S[b,i,j] = sum_r P[b,i,r]*Fn[b,j,r], masked -> fp32
// ===========================================================================
__global__ __launch_bounds__(256)
void k_mf_abt(const u16* __restrict__ Ph, const u16* __restrict__ Pl,
              const u16* __restrict__ Fh, const u16* __restrict__ Fl,
              const int* __restrict__ adj, float* __restrict__ S)
{
    __shared__ u16 Ash[BM * LDT], Asl[BM * LDT];
    __shared__ u16 Bsh[BN * LDT], Bsl[BN * LDT];
    const int t = threadIdx.x, lane = t & 63, w = t >> 6;
    const int wr = w >> 1, wc = w & 1;
    const int b = blockIdx.z;
    const int i0 = blockIdx.y * BM, j0 = blockIdx.x * BN;
    const size_t boff = (size_t)b * N_ * R_;
    const int sr = t >> 1, sc = (t & 1) * 16;
    f32x4 acc[4][4] = {};
    for (int k0 = 0; k0 < R_; k0 += BK) {
        const u16* gah = Ph + boff + (size_t)(i0 + sr) * R_ + k0 + sc;
        const u16* gal = Pl + boff + (size_t)(i0 + sr) * R_ + k0 + sc;
        const u16* gbh = Fh + boff + (size_t)(j0 + sr) * R_ + k0 + sc;
        const u16* gbl = Fl + boff + (size_t)(j0 + sr) * R_ + k0 + sc;
        *(u16x8*)&Ash[sr * LDT + sc]     = *(const u16x8*)(gah);
        *(u16x8*)&Ash[sr * LDT + sc + 8] = *(const u16x8*)(gah + 8);
        *(u16x8*)&Asl[sr * LDT + sc]     = *(const u16x8*)(gal);
        *(u16x8*)&Asl[sr * LDT + sc + 8] = *(const u16x8*)(gal + 8);
        *(u16x8*)&Bsh[sr * LDT + sc]     = *(const u16x8*)(gbh);
        *(u16x8*)&Bsh[sr * LDT + sc + 8] = *(const u16x8*)(gbh + 8);
        *(u16x8*)&Bsl[sr * LDT + sc]     = *(const u16x8*)(gbl);
        *(u16x8*)&Bsl[sr * LDT + sc + 8] = *(const u16x8*)(gbl + 8);
        __syncthreads();
        MFMA_TRIPLE(Ash, Asl, Bsh, Bsl)
        __syncthreads();
    }
    const int cl = lane & 15, rh = lane >> 4;
    const int*  adjb = adj + (size_t)b * N_ * N_;
    float*      Sb   = S   + (size_t)b * N_ * N_;
    #pragma unroll
    for (int m = 0; m < 4; ++m)
        #pragma unroll
        for (int n = 0; n < 4; ++n)
            #pragma unroll
            for (int q = 0; q < 4; ++q) {
                const int row = i0 + wr * 64 + m * 16 + rh * 4 + q;
                const int col = j0 + wc * 64 + n * 16 + cl;
                const size_t idx = (size_t)row * N_ + col;
                Sb[idx] = adjb[idx] ? acc[m][n][q] : -1.0e8f;
            }
}

// ===========================================================================
// Column stats over axis i: m_j, invD_j  (fp32)
// ===========================================================================
__global__ __launch_bounds__(256)
void k_colstats(const float* __restrict__ S, float* __restrict__ mj,
                float* __restrict__ invD)
{
    __shared__ float lm[4][64], ls[4][64];
    const int t = threadIdx.x;
    const int q = t >> 6, c = t & 63;
    const int b = blockIdx.x >> 3;
    const int j = (blockIdx.x & 7) * 64 + c;
    const float* Sb = S + (size_t)b * N_ * N_ + j;
    float m = -3.0e38f, s = 0.0f;
    for (int i = q * 128; i < q * 128 + 128; ++i) {
        const float v = Sb[(size_t)i * N_];
        const float nm = fmaxf(m, v);
        s = s * __expf(m - nm) + __expf(v - nm);
        m = nm;
    }
    lm[q][c] = m; ls[q][c] = s;
    __syncthreads();
    if (q == 0) {
        float M = lm[0][c];
        #pragma unroll
        for (int k = 1; k < 4; ++k) M = fmaxf(M, lm[k][c]);
        float D = 0.0f;
        #pragma unroll
        for (int k = 0; k < 4; ++k) D += ls[k][c] * __expf(lm[k][c] - M);
        mj[(size_t)b * N_ + j]   = M;
        invD[(size_t)b * N_ + j] = 1.0f / D;
    }
}

// ===========================================================================
// Out = (Fn + softmax(S) @ Fn) * F1 ; A staged from fp32 S (exp-normalized,
// split hi/lo), B = FT hi/lo; output split hi/lo
// ===========================================================================
__global__ __launch_bounds__(256)
void k_mf_af(const float* __restrict__ S, const float* __restrict__ mj,
             const float* __restrict__ invD,
             const u16* __restrict__ FTh, const u16* __restrict__ FTl,
             const u16* __restrict__ Fh, const u16* __restrict__ Fl,
             const u16* __restrict__ F1h, const u16* __restrict__ F1l,
             u16* __restrict__ Oh, u16* __restrict__ Ol)
{
    __shared__ u16 Ash[BM * LDT], Asl[BM * LDT];
    __shared__ u16 Bsh[BN * LDT], Bsl[BN * LDT];
    const int t = threadIdx.x, lane = t & 63, w = t >> 6;
    const int wr = w >> 1, wc = w & 1;
    const int b = blockIdx.z;
    const int i0 = blockIdx.y * BM, r0 = blockIdx.x * BN;
    const float* Sb  = S    + (size_t)b * N_ * N_;
    const float* mb  = mj   + (size_t)b * N_;
    const float* db  = invD + (size_t)b * N_;
    const size_t tboff = (size_t)b * R_ * N_;
    const int sr = t >> 1, sc = (t & 1) * 16;
    f32x4 acc[4][4] = {};
    for (int k0 = 0; k0 < N_; k0 += BK) {          // k = j
        const float* gs = Sb + (size_t)(i0 + sr) * N_ + k0 + sc;
        const float* gm = mb + k0 + sc;
        const float* gd = db + k0 + sc;
        #pragma unroll
        for (int h = 0; h < 2; ++h) {
            u16x8 vh, vl;
            #pragma unroll
            for (int p4 = 0; p4 < 2; ++p4) {
                const float4 sv = *(const float4*)(gs + h * 8 + p4 * 4);
                const float4 mv = *(const float4*)(gm + h * 8 + p4 * 4);
                const float4 dv = *(const float4*)(gd + h * 8 + p4 * 4);
                u16 th, tl;
                split2(__expf(sv.x - mv.x) * dv.x, th, tl); vh[p4 * 4 + 0] = th; vl[p4 * 4 + 0] = tl;
                split2(__expf(sv.y - mv.y) * dv.y, th, tl); vh[p4 * 4 + 1] = th; vl[p4 * 4 + 1] = tl;
                split2(__expf(sv.z - mv.z) * dv.z, th, tl); vh[p4 * 4 + 2] = th; vl[p4 * 4 + 2] = tl;
                split2(__expf(sv.w - mv.w) * dv.w, th, tl); vh[p4 * 4 + 3] = th; vl[p4 * 4 + 3] = tl;
            }
            *(u16x8*)&Ash[sr * LDT + sc + h * 8] = vh;
            *(u16x8*)&Asl[sr * LDT + sc + h * 8] = vl;
        }
        const u16* gbh = FTh + tboff + (size_t)(r0 + sr) * N_ + k0 + sc;
        const u16* gbl = FTl + tboff + (size_t)(r0 + sr) * N_ + k0 + sc;
        *(u16x8*)&Bsh[sr * LDT + sc]     = *(const u16x8*)(gbh);
        *(u16x8*)&Bsh[sr * LDT + sc + 8] = *(const u16x8*)(gbh + 8);
        *(u16x8*)&Bsl[sr * LDT + sc]     = *(const u16x8*)(gbl);
        *(u16x8*)&Bsl[sr * LDT + sc + 8] = *(const u16x8*)(gbl + 8);
        __syncthreads();
        MFMA_TRIPLE(Ash, Asl, Bsh, Bsl)
        __syncthreads();
    }
    const int cl = lane & 15, rh = lane >> 4;
    #pragma unroll
    for (int m = 0; m < 4; ++m)
        #pragma unroll
        for (int n = 0; n < 4; ++n)
            #pragma unroll
            for (int q = 0; q < 4; ++q) {
                const int row = i0 + wr * 64 + m * 16 + rh * 4 + q;
                const int col = r0 + wc * 64 + n * 16 + cl;
                const size_t idx = ((size_t)b * N_ + row) * R_ + col;
                const float fn = join2(Fh[idx], Fl[idx]);
                const float f1 = join2(F1h[idx], F1l[idx]);
                split2((fn + acc[m][n][q]) * f1, Oh[idx], Ol[idx]);
            }
}

// ===========================================================================
// g = silu(X @ Wg + bg); f[b, step*R + n] += sum_rows g
// ===========================================================================
__global__ __launch_bounds__(256)
void k_mf_wg(const u16* __restrict__ Xh, const u16* __restrict__ Xl,
             const u16* __restrict__ WgTh, const u16* __restrict__ WgTl,
             const float* __restrict__ bg, float* __restrict__ f, int step)
{
    __shared__ u16 Ash[BM * LDT], Asl[BM * LDT];
    __shared__ u16 Bsh[BN * LDT], Bsl[BN * LDT];
    const int t = threadIdx.x, lane = t & 63, w = t >> 6;
    const int wr = w >> 1, wc = w & 1;
    const int m0 = blockIdx.y * BM, n0 = blockIdx.x * BN;
    const int sr = t >> 1, sc = (t & 1) * 16;
    f32x4 acc[4][4] = {};
    for (int k0 = 0; k0 < R_; k0 += BK) {
        const u16* gah = Xh + (size_t)(m0 + sr) * R_ + k0 + sc;
        const u16* gal = Xl + (size_t)(m0 + sr) * R_ + k0 + sc;
        const u16* gbh = WgTh + (size_t)(n0 + sr) * R_ + k0 + sc;
        const u16* gbl = WgTl + (size_t)(n0 + sr) * R_ + k0 + sc;
        *(u16x8*)&Ash[sr * LDT + sc]     = *(const u16x8*)(gah);
        *(u16x8*)&Ash[sr * LDT + sc + 8] = *(const u16x8*)(gah + 8);
        *(u16x8*)&Asl[sr * LDT + sc]     = *(const u16x8*)(gal);
        *(u16x8*)&Asl[sr * LDT + sc + 8] = *(const u16x8*)(gal + 8);
        *(u16x8*)&Bsh[sr * LDT + sc]     = *(const u16x8*)(gbh);
        *(u16x8*)&Bsh[sr * LDT + sc + 8] = *(const u16x8*)(gbh + 8);
        *(u16x8*)&Bsl[sr * LDT + sc]     = *(const u16x8*)(gbl);
        *(u16x8*)&Bsl[sr * LDT + sc + 8] = *(const u16x8*)(gbl + 8);
        __syncthreads();
        MFMA_TRIPLE(Ash, Asl, Bsh, Bsl)
        __syncthreads();
    }
    const int cl = lane & 15, rh = lane >> 4;
    const int bb = blockIdx.y >> 2;              // 4 row-tiles of 128 per batch
    #pragma unroll
    for (int n = 0; n < 4; ++n) {
        const int col = n0 + wc * 64 + n * 16 + cl;
        const float bias = bg[col];
        float s = 0.0f;
        #pragma unroll
        for (int m = 0; m < 4; ++m)
            #pragma unroll
            for (int q = 0; q < 4; ++q)
                s += silu_f(acc[m][n][q] + bias);
        s += __shfl_xor(s, 16);
        s += __shfl_xor(s, 32);
        if (rh == 0)
            atomicAdd(&f[(size_t)bb * HID_ + step * R_ + col], s);
    }
}

// ===========================================================================
// u16 plane transpose, both planes in one launch (z bit selects plane):
// FT[b,r,i] = Fn[b,i,r]
// ===========================================================================
#define TLD 72
__global__ __launch_bounds__(256)
void k_transpose_bf2(const u16* __restrict__ F0, const u16* __restrict__ F1p,
                     u16* __restrict__ T0, u16* __restrict__ T1p)
{
    __shared__ u16 tile[64 * TLD];
    const int pl = blockIdx.z & 1;
    const int b  = blockIdx.z >> 1;
    const u16* Fn = pl ? F1p : F0;
    u16*       FT = pl ? T1p : T0;
    const int i0 = blockIdx.y * 64;
    const int r0 = blockIdx.x * 64;
    const u16* src = Fn + ((size_t)b * N_ + i0) * R_ + r0;
    u16*       dst = FT + ((size_t)b * R_ + r0) * N_ + i0;
    const int t = threadIdx.x;
    const int rr = t >> 2, cc = (t & 3) * 16;
    *(u16x8*)&tile[rr * TLD + cc]     = *(const u16x8*)(src + (size_t)rr * R_ + cc);
    *(u16x8*)&tile[rr * TLD + cc + 8] = *(const u16x8*)(src + (size_t)rr * R_ + cc + 8);
    __syncthreads();
    const int ro = t >> 2, co = (t & 3) * 16;
    u16x8 v0, v1;
    #pragma unroll
    for (int q = 0; q < 8; ++q) v0[q] = tile[(co + q) * TLD + ro];
    #pragma unroll
    for (int q = 0; q < 8; ++q) v1[q] = tile[(co + 8 + q) * TLD + ro];
    *(u16x8*)(dst + (size_t)ro * N_ + co)     = v0;
    *(u16x8*)(dst + (size_t)ro * N_ + co + 8) = v1;
}

// WT[n,k] hi/lo = split(W[k,n])
__global__ __launch_bounds__(256)
void k_cvt_wT(const float* __restrict__ Win, u16* __restrict__ WTh,
              u16* __restrict__ WTl, int K, int Nn)
{
    const int idx = blockIdx.x * 256 + threadIdx.x;
    if (idx < K * Nn) {
        const int n = idx / K, k = idx % K;
        split2(Win[(size_t)k * Nn + n], WTh[idx], WTl[idx]);
    }
}

// ===========================================================================
// Split-K fp32 GEMM for the thin MLP head (M=64). 64x64 tile over a K-slice,
// partials to Part[sk][M*Nn]; reduce kernel applies bias + activation.
// ===========================================================================
#define TS 64
#define FBK 16
__global__ __launch_bounds__(256)
void k_gemm_splitk(const float* __restrict__ A, const float* __restrict__ W,
                   float* __restrict__ Part, int M, int Nn, int K, int klen)
{
    __shared__ float As[FBK][TS];
    __shared__ float Ws[FBK][TS];
    const int tx = threadIdx.x, ty = threadIdx.y;
    const int t  = ty * 16 + tx;
    const int n0 = blockIdx.x * TS;
    const int kb = blockIdx.z * klen;
    const int alm = t >> 2, alk = (t & 3) * 4;
    const int wr  = t >> 4, wc  = (t & 15) * 4;
    float acc[4][4] = {};
    for (int k0 = kb; k0 < kb + klen; k0 += FBK) {
        float4 av = *(const float4*)(A + (size_t)alm * K + k0 + alk);
        As[alk + 0][alm] = av.x; As[alk + 1][alm] = av.y;
        As[alk + 2][alm] = av.z; As[alk + 3][alm] = av.w;
        *(float4*)(&Ws[wr][wc]) = *(const float4*)(W + (size_t)(k0 + wr) * Nn + n0 + wc);
        __syncthreads();
        #pragma unroll
        for (int k = 0; k < FBK; ++k) {
            float a[4], w2[4];
            #pragma unroll
            for (int q = 0; q < 4; ++q) { a[q] = As[k][ty * 4 + q]; w2[q] = Ws[k][tx * 4 + q]; }
            #pragma unroll
            for (int ii = 0; ii < 4; ++ii)
                #pragma unroll
                for (int jj = 0; jj < 4; ++jj)
                    acc[ii][jj] = fmaf(a[ii], w2[jj], acc[ii][jj]);
        }
        __syncthreads();
    }
    float* Pb = Part + (size_t)blockIdx.z * M * Nn;
    #pragma unroll
    for (int ii = 0; ii < 4; ++ii) {
        const int m = ty * 4 + ii;
        #pragma unroll
        for (int jj = 0; jj < 4; ++jj)
            Pb[(size_t)m * Nn + n0 + tx * 4 + jj] = acc[ii][jj];
    }
}

template<int ACT>
__global__ __launch_bounds__(256)
void k_reduce_bias_act(const float* __restrict__ Part, const float* __restrict__ bias,
                       float* __restrict__ C, int MN, int Nn, int SK)
{
    const int i = blockIdx.x * 256 + threadIdx.x;
    if (i < MN) {
        float s = 0.0f;
        for (int k = 0; k < SK; ++k) s += Part[(size_t)k * MN + i];
        float v = s + bias[i % Nn];
        if (ACT) v = silu_f(v);
        C[i] = v;
    }
}

__global__ __launch_bounds__(256)
void k_rownorm(float* __restrict__ f)
{
    __shared__ float red[256];
    const int b = blockIdx.x, t = threadIdx.x;
    float ss = 0.0f;
    for (int c = t; c < HID_; c += 256) {
        const float v = f[(size_t)b * HID_ + c];
        ss += v * v;
    }
    red[t] = ss;
    __syncthreads();
    for (int o = 128; o > 0; o >>= 1) {
        if (t < o) red[t] += red[t + o];
        __syncthreads();
    }
    const float inv = 1.0f / fmaxf(sqrtf(red[0]), 1e-12f);
    for (int c = t; c < HID_; c += 256)
        f[(size_t)b * HID_ + c] *= inv;
}

// ===========================================================================
extern "C" void kernel_launch(void* const* d_in, const int* in_sizes, int n_in,
                              void* d_out, int out_size, void* d_ws, size_t ws_size,
                              hipStream_t stream)
{
    const float* node = (const float*)d_in[0];
    const int*   adj  = (const int*)d_in[1];
    const float* Wv_w = (const float*)d_in[3];  const float* Wv_b = (const float*)d_in[4];
    const float* Ww_w = (const float*)d_in[5];  const float* Ww_b = (const float*)d_in[6];
    const float* Wg_w = (const float*)d_in[7];  const float* Wg_b = (const float*)d_in[8];
    const float* W0 = (const float*)d_in[9];    const float* b0 = (const float*)d_in[10];
    const float* W1 = (const float*)d_in[11];   const float* b1 = (const float*)d_in[12];
    const float* W2 = (const float*)d_in[13];   const float* b2 = (const float*)d_in[14];
    const float* W3 = (const float*)d_in[15];   const float* b3 = (const float*)d_in[16];
    float* out = (float*)d_out;

    float* ws = (float*)d_ws;
    const size_t SZ = (size_t)B_ * N_ * R_;              // 8,388,608 elems
    float* S     = ws;                                   // B*N*N fp32 (walk loop)
    float* h0    = ws;                                   // alias S (post-loop)
    float* h1    = ws + 98304;
    float* h2    = ws + 196608;
    float* Part  = ws + 262144;                          // 16*98304 = 1.57M floats
    float* mj    = ws + (size_t)B_ * N_ * N_;            // 32768
    float* invD  = mj + 32768;
    float* f     = invD + 32768;                         // 98304
    u16* u0   = (u16*)(f + 98304);
    u16* F1h  = u0;            u16* F1l  = F1h + SZ;
    u16* X1h  = F1l + SZ;      u16* X1l  = X1h + SZ;
    u16* X2h  = X1l + SZ;      u16* X2l  = X2h + SZ;
    u16* XTh  = X2l + SZ;      u16* XTl  = XTh + SZ;
    u16* Ph   = XTl + SZ;      u16* Pl   = Ph + SZ;
    u16* WvTh = Pl + SZ;       u16* WvTl = WvTh + 65536;
    u16* WwTh = WvTl + 65536;  u16* WwTl = WwTh + 65536;
    u16* WgTh = WwTl + 65536;  u16* WgTl = WgTh + 65536;

    // --- weight splits (once per launch) ---
    k_cvt_wT<<<256, 256, 0, stream>>>(Wv_w, WvTh, WvTl, 256, 256);
    k_cvt_wT<<<256, 256, 0, stream>>>(Ww_w, WwTh, WwTl, 256, 256);
    k_cvt_wT<<<256, 256, 0, stream>>>(Wg_w, WgTh, WgTl, 256, 256);
    (void)hipMemsetAsync(f, 0, 98304 * sizeof(float), stream);

    // --- F1 = silu(node @ Wv + b)  (A = fp32 node, on-the-fly split) ---
    k_mf_gemm<1, 1><<<dim3(2, 256), 256, 0, stream>>>(
        node, nullptr, nullptr, WvTh, WvTl, Wv_b, F1h, F1l, B_ * N_, R_, 256);
    k_mf_wg<<<dim3(2, 256), 256, 0, stream>>>(F1h, F1l, WgTh, WgTl, Wg_b, f, 0);
    k_transpose_bf2<<<dim3(4, 8, 128), 256, 0, stream>>>(F1h, F1l, XTh, XTl);

    const u16 *Xh = F1h, *Xl = F1l;
    u16 *Yh = X1h, *Yl = X1l;
    for (int step = 1; step < L_; ++step) {
        k_mf_gemm<0, 0><<<dim3(2, 256), 256, 0, stream>>>(
            nullptr, Xh, Xl, WwTh, WwTl, Ww_b, Ph, Pl, B_ * N_, R_, 256);
        k_mf_abt<<<dim3(4, 4, 64), 256, 0, stream>>>(Ph, Pl, Xh, Xl, adj, S);
        k_colstats<<<512, 256, 0, stream>>>(S, mj, invD);
        k_mf_af<<<dim3(2, 4, 64), 256, 0, stream>>>(
            S, mj, invD, XTh, XTl, Xh, Xl, F1h, F1l, Yh, Yl);
        k_mf_wg<<<dim3(2, 256), 256, 0, stream>>>(Yh, Yl, WgTh, WgTl, Wg_b, f, step);
        if (step < L_ - 1)
            k_transpose_bf2<<<dim3(4, 8, 128), 256, 0, stream>>>(Yh, Yl, XTh, XTl);
        const u16 *nxh = Yh, *nxl = Yl;
        if (step == 1) { Yh = X2h; Yl = X2l; }
        else           { Yh = (u16*)Xh; Yl = (u16*)Xl; }
        Xh = nxh; Xl = nxl;
    }

    k_rownorm<<<B_, 256, 0, stream>>>(f);

    // --- MLP head (fp32 split-K): 1536 -> 1536 -> 768 -> 128 ---
    const dim3 fblk(16, 16);
    k_gemm_splitk<<<dim3(24, 1, 16), fblk, 0, stream>>>(f,  W0, Part, B_, HID_, HID_, 96);
    k_reduce_bias_act<1><<<384, 256, 0, stream>>>(Part, b0, h0, B_ * HID_, HID_, 16);
    k_gemm_splitk<<<dim3(24, 1, 16), fblk, 0, stream>>>(h0, W1, Part, B_, HID_, HID_, 96);
    k_reduce_bias_act<1><<<384, 256, 0, stream>>>(Part, b1, h1, B_ * HID_, HID_, 16);
    k_gemm_splitk<<<dim3(12, 1, 16), fblk, 0, stream>>>(h1, W2, Part, B_, 768, HID_, 96);
    k_reduce_bias_act<1><<<192, 256, 0, stream>>>(Part, b2, h2, B_ * 768, 768, 16);
    k_gemm_splitk<<<dim3(2, 1, 8),   fblk, 0, stream>>>(h2, W3, Part, B_, 128, 768, 96);
    k_reduce_bias_act<0><<<32, 256, 0, stream>>>(Part, b3, out, B_ * 128, 128, 8);
}

// Round 10
// 1039.869 us; speedup vs baseline: 2.6927x; 1.0577x over previous
//
#include <hip/hip_runtime.h>

#define B_   64
#define N_   512
#define R_   256
#define L_   6
#define HID_ 1536

#define BM 128
#define BN 128
#define BK 32
#define LDT 40   // padded LDS stride (u16 elems); 2-way bank alias only = free

typedef __attribute__((ext_vector_type(4))) float f32x4;
typedef __attribute__((ext_vector_type(8))) __bf16 bf16x8;
typedef __attribute__((ext_vector_type(8))) unsigned short u16x8;
typedef unsigned short u16;
typedef unsigned char  u8;
typedef unsigned int   u32;

__device__ __forceinline__ float silu_f(float x) { return x / (1.0f + __expf(-x)); }

__device__ __forceinline__ float bf2f(u16 h) {
    u32 u = ((u32)h) << 16;
    return __builtin_bit_cast(float, u);
}
// truncation split: x ~= hi + lo with ~17 effective mantissa bits
__device__ __forceinline__ void split2(float x, u16& h, u16& l) {
    u32 u = __builtin_bit_cast(u32, x);
    h = (u16)(u >> 16);
    float r = x - __builtin_bit_cast(float, u & 0xffff0000u);   // exact
    l = (u16)(__builtin_bit_cast(u32, r) >> 16);
}
__device__ __forceinline__ float join2(u16 h, u16 l) {
    return bf2f(h) + bf2f(l);
}

// ===========================================================================
// Split-GEMM core helper: acc += Ah*Bh + Al*Bh + Ah*Bl
// ===========================================================================
#define MFMA_TRIPLE(Ash, Asl, Bsh, Bsl)                                         \
    {                                                                           \
        const int k8 = (lane >> 4) * 8, cl = lane & 15;                         \
        bf16x8 bh[4], bl[4];                                                    \
        _Pragma("unroll")                                                       \
        for (int n = 0; n < 4; ++n) {                                           \
            bh[n] = *(const bf16x8*)&Bsh[(wc * 64 + n * 16 + cl) * LDT + k8];   \
            bl[n] = *(const bf16x8*)&Bsl[(wc * 64 + n * 16 + cl) * LDT + k8];   \
        }                                                                       \
        _Pragma("unroll")                                                       \
        for (int m = 0; m < 4; ++m) {                                           \
            bf16x8 ah = *(const bf16x8*)&Ash[(wr * 64 + m * 16 + cl) * LDT + k8]; \
            bf16x8 al = *(const bf16x8*)&Asl[(wr * 64 + m * 16 + cl) * LDT + k8]; \
            _Pragma("unroll")                                                   \
            for (int n = 0; n < 4; ++n) {                                       \
                acc[m][n] = __builtin_amdgcn_mfma_f32_16x16x32_bf16(ah, bh[n], acc[m][n], 0, 0, 0); \
                acc[m][n] = __builtin_amdgcn_mfma_f32_16x16x32_bf16(al, bh[n], acc[m][n], 0, 0, 0); \
                acc[m][n] = __builtin_amdgcn_mfma_f32_16x16x32_bf16(ah, bl[n], acc[m][n], 0, 0, 0); \
            }                                                                   \
        }                                                                       \
    }

// ===========================================================================
// C = act(A @ W + bias), A: fp32 (AFP32=1, on-the-fly split) or hi/lo pair.
// W pre-split as WT[Nn,K] hi/lo. Output written as hi/lo pair.
// ===========================================================================
template<int ACT, int AFP32>
__global__ __launch_bounds__(256)
void k_mf_gemm(const float* __restrict__ Af,
               const u16* __restrict__ Ah, const u16* __restrict__ Al,
               const u16* __restrict__ WTh, const u16* __restrict__ WTl,
               const float* __restrict__ bias,
               u16* __restrict__ Ch, u16* __restrict__ Cl,
               int M, int Nn, int K)
{
    __shared__ u16 Ash[BM * LDT], Asl[BM * LDT];
    __shared__ u16 Bsh[BN * LDT], Bsl[BN * LDT];
    const int t = threadIdx.x, lane = t & 63, w = t >> 6;
    const int wr = w >> 1, wc = w & 1;
    const int m0 = blockIdx.y * BM, n0 = blockIdx.x * BN;
    const int sr = t >> 1, sc = (t & 1) * 16;
    f32x4 acc[4][4] = {};
    for (int k0 = 0; k0 < K; k0 += BK) {
        if (AFP32) {
            const float* ga = Af + (size_t)(m0 + sr) * K + k0 + sc;
            u16x8 vh0, vl0, vh1, vl1;
            #pragma unroll
            for (int p = 0; p < 2; ++p) {
                const float4 a = *(const float4*)(ga + p * 8);
                const float4 b = *(const float4*)(ga + p * 8 + 4);
                u16 h, l;
                split2(a.x, h, l); (p ? vh1 : vh0)[0] = h; (p ? vl1 : vl0)[0] = l;
                split2(a.y, h, l); (p ? vh1 : vh0)[1] = h; (p ? vl1 : vl0)[1] = l;
                split2(a.z, h, l); (p ? vh1 : vh0)[2] = h; (p ? vl1 : vl0)[2] = l;
                split2(a.w, h, l); (p ? vh1 : vh0)[3] = h; (p ? vl1 : vl0)[3] = l;
                split2(b.x, h, l); (p ? vh1 : vh0)[4] = h; (p ? vl1 : vl0)[4] = l;
                split2(b.y, h, l); (p ? vh1 : vh0)[5] = h; (p ? vl1 : vl0)[5] = l;
                split2(b.z, h, l); (p ? vh1 : vh0)[6] = h; (p ? vl1 : vl0)[6] = l;
                split2(b.w, h, l); (p ? vh1 : vh0)[7] = h; (p ? vl1 : vl0)[7] = l;
            }
            *(u16x8*)&Ash[sr * LDT + sc]     = vh0;
            *(u16x8*)&Ash[sr * LDT + sc + 8] = vh1;
            *(u16x8*)&Asl[sr * LDT + sc]     = vl0;
            *(u16x8*)&Asl[sr * LDT + sc + 8] = vl1;
        } else {
            const u16* gah = Ah + (size_t)(m0 + sr) * K + k0 + sc;
            const u16* gal = Al + (size_t)(m0 + sr) * K + k0 + sc;
            *(u16x8*)&Ash[sr * LDT + sc]     = *(const u16x8*)(gah);
            *(u16x8*)&Ash[sr * LDT + sc + 8] = *(const u16x8*)(gah + 8);
            *(u16x8*)&Asl[sr * LDT + sc]     = *(const u16x8*)(gal);
            *(u16x8*)&Asl[sr * LDT + sc + 8] = *(const u16x8*)(gal + 8);
        }
        const u16* gbh = WTh + (size_t)(n0 + sr) * K + k0 + sc;
        const u16* gbl = WTl + (size_t)(n0 + sr) * K + k0 + sc;
        *(u16x8*)&Bsh[sr * LDT + sc]     = *(const u16x8*)(gbh);
        *(u16x8*)&Bsh[sr * LDT + sc + 8] = *(const u16x8*)(gbh + 8);
        *(u16x8*)&Bsl[sr * LDT + sc]     = *(const u16x8*)(gbl);
        *(u16x8*)&Bsl[sr * LDT + sc + 8] = *(const u16x8*)(gbl + 8);
        __syncthreads();
        MFMA_TRIPLE(Ash, Asl, Bsh, Bsl)
        __syncthreads();
    }
    const int cl = lane & 15, rh = lane >> 4;
    #pragma unroll
    for (int m = 0; m < 4; ++m)
        #pragma unroll
        for (int n = 0; n < 4; ++n) {
            const int col = n0 + wc * 64 + n * 16 + cl;
            const float bb = bias[col];
            #pragma unroll
            for (int q = 0; q < 4; ++q) {
                const int row = m0 + wr * 64 + m * 16 + rh * 4 + q;
                float v = acc[m][n][q] + bb;
                if (ACT) v = silu_f(v);
                const size_t idx = (size_t)row * Nn + col;
                split2(v, Ch[idx], Cl[idx]);
            }
        }
}

// ===========================================================================
// S[b,i,j] = sum_r P[b,i,r]*Fn[b,j,r], masked by u8 msk -> fp32
// ===========================================================================
__global__ __launch_bounds__(256)
void k_mf_abt(const u16* __restrict__ Ph, const u16* __restrict__ Pl,
              const u16* __restrict__ Fh, const u16* __restrict__ Fl,
              const u8* __restrict__ msk, float* __restrict__ S)
{
    __shared__ u16 Ash[BM * LDT], Asl[BM * LDT];
    __shared__ u16 Bsh[BN * LDT], Bsl[BN * LDT];
    const int t = threadIdx.x, lane = t & 63, w = t >> 6;
    const int wr = w >> 1, wc = w & 1;
    const int b = blockIdx.z;
    const int i0 = blockIdx.y * BM, j0 = blockIdx.x * BN;
    const size_t boff = (size_t)b * N_ * R_;
    const int sr = t >> 1, sc = (t & 1) * 16;
    f32x4 acc[4][4] = {};
    for (int k0 = 0; k0 < R_; k0 += BK) {
        const u16* gah = Ph + boff + (size_t)(i0 + sr) * R_ + k0 + sc;
        const u16* gal = Pl + boff + (size_t)(i0 + sr) * R_ + k0 + sc;
        const u16* gbh = Fh + boff + (size_t)(j0 + sr) * R_ + k0 + sc;
        const u16* gbl = Fl + boff + (size_t)(j0 + sr) * R_ + k0 + sc;
        *(u16x8*)&Ash[sr * LDT + sc]     = *(const u16x8*)(gah);
        *(u16x8*)&Ash[sr * LDT + sc + 8] = *(const u16x8*)(gah + 8);
        *(u16x8*)&Asl[sr * LDT + sc]     = *(const u16x8*)(gal);
        *(u16x8*)&Asl[sr * LDT + sc + 8] = *(const u16x8*)(gal + 8);
        *(u16x8*)&Bsh[sr * LDT + sc]     = *(const u16x8*)(gbh);
        *(u16x8*)&Bsh[sr * LDT + sc + 8] = *(const u16x8*)(gbh + 8);
        *(u16x8*)&Bsl[sr * LDT + sc]     = *(const u16x8*)(gbl);
        *(u16x8*)&Bsl[sr * LDT + sc + 8] = *(const u16x8*)(gbl + 8);
        __syncthreads();
        MFMA_TRIPLE(Ash, Asl, Bsh, Bsl)
        __syncthreads();
    }
    const int cl = lane & 15, rh = lane >> 4;
    const u8*   mb = msk + (size_t)b * N_ * N_;
    float*      Sb = S   + (size_t)b * N_ * N_;
    #pragma unroll
    for (int m = 0; m < 4; ++m)
        #pragma unroll
        for (int n = 0; n < 4; ++n)
            #pragma unroll
            for (int q = 0; q < 4; ++q) {
                const int row = i0 + wr * 64 + m * 16 + rh * 4 + q;
                const int col = j0 + wc * 64 + n * 16 + cl;
                const size_t idx = (size_t)row * N_ + col;
                Sb[idx] = mb[idx] ? acc[m][n][q] : -1.0e8f;
            }
}

// ===========================================================================
// Column stats over axis i: m_j, invD_j  (fp32)
// ===========================================================================
__global__ __launch_bounds__(256)
void k_colstats(const float* __restrict__ S, float* __restrict__ mj,
                float* __restrict__ invD)
{
    __shared__ float lm[4][64], ls[4][64];
    const int t = threadIdx.x;
    const int q = t >> 6, c = t & 63;
    const int b = blockIdx.x >> 3;
    const int j = (blockIdx.x & 7) * 64 + c;
    const float* Sb = S + (size_t)b * N_ * N_ + j;
    float m = -3.0e38f, s = 0.0f;
    for (int i = q * 128; i < q * 128 + 128; ++i) {
        const float v = Sb[(size_t)i * N_];
        const float nm = fmaxf(m, v);
        s = s * __expf(m - nm) + __expf(v - nm);
        m = nm;
    }
    lm[q][c] = m; ls[q][c] = s;
    __syncthreads();
    if (q == 0) {
        float M = lm[0][c];
        #pragma unroll
        for (int k = 1; k < 4; ++k) M = fmaxf(M, lm[k][c]);
        float D = 0.0f;
        #pragma unroll
        for (int k = 0; k < 4; ++k) D += ls[k][c] * __expf(lm[k][c] - M);
        mj[(size_t)b * N_ + j]   = M;
        invD[(size_t)b * N_ + j] = 1.0f / D;
    }
}

// ===========================================================================
// Out = (Fn + softmax(S) @ Fn) * F1 ; A staged from fp32 S (exp-normalized,
// split hi/lo), B = FT hi/lo; output split hi/lo
// ===========================================================================
__global__ __launch_bounds__(256)
void k_mf_af(const float* __restrict__ S, const float* __restrict__ mj,
             const float* __restrict__ invD,
             const u16* __restrict__ FTh, const u16* __restrict__ FTl,
             const u16* __restrict__ Fh, const u16* __restrict__ Fl,
             const u16* __restrict__ F1h, const u16* __restrict__ F1l,
             u16* __restrict__ Oh, u16* __restrict__ Ol)
{
    __shared__ u16 Ash[BM * LDT], Asl[BM * LDT];
    __shared__ u16 Bsh[BN * LDT], Bsl[BN * LDT];
    const int t = threadIdx.x, lane = t & 63, w = t >> 6;
    const int wr = w >> 1, wc = w & 1;
    const int b = blockIdx.z;
    const int i0 = blockIdx.y * BM, r0 = blockIdx.x * BN;
    const float* Sb  = S    + (size_t)b * N_ * N_;
    const float* mb  = mj   + (size_t)b * N_;
    const float* db  = invD + (size_t)b * N_;
    const size_t tboff = (size_t)b * R_ * N_;
    const int sr = t >> 1, sc = (t & 1) * 16;
    f32x4 acc[4][4] = {};
    for (int k0 = 0; k0 < N_; k0 += BK) {          // k = j
        const float* gs = Sb + (size_t)(i0 + sr) * N_ + k0 + sc;
        const float* gm = mb + k0 + sc;
        const float* gd = db + k0 + sc;
        #pragma unroll
        for (int h = 0; h < 2; ++h) {
            u16x8 vh, vl;
            #pragma unroll
            for (int p4 = 0; p4 < 2; ++p4) {
                const float4 sv = *(const float4*)(gs + h * 8 + p4 * 4);
                const float4 mv = *(const float4*)(gm + h * 8 + p4 * 4);
                const float4 dv = *(const float4*)(gd + h * 8 + p4 * 4);
                u16 th, tl;
                split2(__expf(sv.x - mv.x) * dv.x, th, tl); vh[p4 * 4 + 0] = th; vl[p4 * 4 + 0] = tl;
                split2(__expf(sv.y - mv.y) * dv.y, th, tl); vh[p4 * 4 + 1] = th; vl[p4 * 4 + 1] = tl;
                split2(__expf(sv.z - mv.z) * dv.z, th, tl); vh[p4 * 4 + 2] = th; vl[p4 * 4 + 2] = tl;
                split2(__expf(sv.w - mv.w) * dv.w, th, tl); vh[p4 * 4 + 3] = th; vl[p4 * 4 + 3] = tl;
            }
            *(u16x8*)&Ash[sr * LDT + sc + h * 8] = vh;
            *(u16x8*)&Asl[sr * LDT + sc + h * 8] = vl;
        }
        const u16* gbh = FTh + tboff + (size_t)(r0 + sr) * N_ + k0 + sc;
        const u16* gbl = FTl + tboff + (size_t)(r0 + sr) * N_ + k0 + sc;
        *(u16x8*)&Bsh[sr * LDT + sc]     = *(const u16x8*)(gbh);
        *(u16x8*)&Bsh[sr * LDT + sc + 8] = *(const u16x8*)(gbh + 8);
        *(u16x8*)&Bsl[sr * LDT + sc]     = *(const u16x8*)(gbl);
        *(u16x8*)&Bsl[sr * LDT + sc + 8] = *(const u16x8*)(gbl + 8);
        __syncthreads();
        MFMA_TRIPLE(Ash, Asl, Bsh, Bsl)
        __syncthreads();
    }
    const int cl = lane & 15, rh = lane >> 4;
    #pragma unroll
    for (int m = 0; m < 4; ++m)
        #pragma unroll
        for (int n = 0; n < 4; ++n)
            #pragma unroll
            for (int q = 0; q < 4; ++q) {
                const int row = i0 + wr * 64 + m * 16 + rh * 4 + q;
                const int col = r0 + wc * 64 + n * 16 + cl;
                const size_t idx = ((size_t)b * N_ + row) * R_ + col;
                const float fn = join2(Fh[idx], Fl[idx]);
                const float f1 = join2(F1h[idx], F1l[idx]);
                split2((fn + acc[m][n][q]) * f1, Oh[idx], Ol[idx]);
            }
}

// ===========================================================================
// g = silu(X @ Wg + bg); f[b, step*R + n] += sum_rows g
// ===========================================================================
__global__ __launch_bounds__(256)
void k_mf_wg(const u16* __restrict__ Xh, const u16* __restrict__ Xl,
             const u16* __restrict__ WgTh, const u16* __restrict__ WgTl,
             const float* __restrict__ bg, float* __restrict__ f, int step)
{
    __shared__ u16 Ash[BM * LDT], Asl[BM * LDT];
    __shared__ u16 Bsh[BN * LDT], Bsl[BN * LDT];
    const int t = threadIdx.x, lane = t & 63, w = t >> 6;
    const int wr = w >> 1, wc = w & 1;
    const int m0 = blockIdx.y * BM, n0 = blockIdx.x * BN;
    const int sr = t >> 1, sc = (t & 1) * 16;
    f32x4 acc[4][4] = {};
    for (int k0 = 0; k0 < R_; k0 += BK) {
        const u16* gah = Xh + (size_t)(m0 + sr) * R_ + k0 + sc;
        const u16* gal = Xl + (size_t)(m0 + sr) * R_ + k0 + sc;
        const u16* gbh = WgTh + (size_t)(n0 + sr) * R_ + k0 + sc;
        const u16* gbl = WgTl + (size_t)(n0 + sr) * R_ + k0 + sc;
        *(u16x8*)&Ash[sr * LDT + sc]     = *(const u16x8*)(gah);
        *(u16x8*)&Ash[sr * LDT + sc + 8] = *(const u16x8*)(gah + 8);
        *(u16x8*)&Asl[sr * LDT + sc]     = *(const u16x8*)(gal);
        *(u16x8*)&Asl[sr * LDT + sc + 8] = *(const u16x8*)(gal + 8);
        *(u16x8*)&Bsh[sr * LDT + sc]     = *(const u16x8*)(gbh);
        *(u16x8*)&Bsh[sr * LDT + sc + 8] = *(const u16x8*)(gbh + 8);
        *(u16x8*)&Bsl[sr * LDT + sc]     = *(const u16x8*)(gbl);
        *(u16x8*)&Bsl[sr * LDT + sc + 8] = *(const u16x8*)(gbl + 8);
        __syncthreads();
        MFMA_TRIPLE(Ash, Asl, Bsh, Bsl)
        __syncthreads();
    }
    const int cl = lane & 15, rh = lane >> 4;
    const int bb = blockIdx.y >> 2;              // 4 row-tiles of 128 per batch
    #pragma unroll
    for (int n = 0; n < 4; ++n) {
        const int col = n0 + wc * 64 + n * 16 + cl;
        const float bias = bg[col];
        float s = 0.0f;
        #pragma unroll
        for (int m = 0; m < 4; ++m)
            #pragma unroll
            for (int q = 0; q < 4; ++q)
                s += silu_f(acc[m][n][q] + bias);
        s += __shfl_xor(s, 16);
        s += __shfl_xor(s, 32);
        if (rh == 0)
            atomicAdd(&f[(size_t)bb * HID_ + step * R_ + col], s);
    }
}

// ===========================================================================
// u16 plane transpose, both planes in one launch (z bit selects plane):
// FT[b,r,i] = Fn[b,i,r]
// ===========================================================================
#define TLD 72
__global__ __launch_bounds__(256)
void k_transpose_bf2(const u16* __restrict__ F0, const u16* __restrict__ F1p,
                     u16* __restrict__ T0, u16* __restrict__ T1p)
{
    __shared__ u16 tile[64 * TLD];
    const int pl = blockIdx.z & 1;
    const int b  = blockIdx.z >> 1;
    const u16* Fn = pl ? F1p : F0;
    u16*       FT = pl ? T1p : T0;
    const int i0 = blockIdx.y * 64;
    const int r0 = blockIdx.x * 64;
    const u16* src = Fn + ((size_t)b * N_ + i0) * R_ + r0;
    u16*       dst = FT + ((size_t)b * R_ + r0) * N_ + i0;
    const int t = threadIdx.x;
    const int rr = t >> 2, cc = (t & 3) * 16;
    *(u16x8*)&tile[rr * TLD + cc]     = *(const u16x8*)(src + (size_t)rr * R_ + cc);
    *(u16x8*)&tile[rr * TLD + cc + 8] = *(const u16x8*)(src + (size_t)rr * R_ + cc + 8);
    __syncthreads();
    const int ro = t >> 2, co = (t & 3) * 16;
    u16x8 v0, v1;
    #pragma unroll
    for (int q = 0; q < 8; ++q) v0[q] = tile[(co + q) * TLD + ro];
    #pragma unroll
    for (int q = 0; q < 8; ++q) v1[q] = tile[(co + 8 + q) * TLD + ro];
    *(u16x8*)(dst + (size_t)ro * N_ + co)     = v0;
    *(u16x8*)(dst + (size_t)ro * N_ + co + 8) = v1;
}

// WT[n,k] hi/lo = split(W[k,n])
__global__ __launch_bounds__(256)
void k_cvt_wT(const float* __restrict__ Win, u16* __restrict__ WTh,
              u16* __restrict__ WTl, int K, int Nn)
{
    const int idx = blockIdx.x * 256 + threadIdx.x;
    if (idx < K * Nn) {
        const int n = idx / K, k = idx % K;
        split2(Win[(size_t)k * Nn + n], WTh[idx], WTl[idx]);
    }
}

// adj int32 -> u8 mask (4 elems/thread)
__global__ __launch_bounds__(256)
void k_adj_mask(const int* __restrict__ adj, u8* __restrict__ msk, int n4)
{
    const int i = blockIdx.x * 256 + threadIdx.x;
    if (i < n4) {
        const int4 a = *(const int4*)(adj + (size_t)i * 4);
        uchar4 m;
        m.x = a.x ? 1 : 0; m.y = a.y ? 1 : 0;
        m.z = a.z ? 1 : 0; m.w = a.w ? 1 : 0;
        *(uchar4*)(msk + (size_t)i * 4) = m;
    }
}

// ===========================================================================
// Split-K fp32 GEMM + reduce for the thin MLP head (M=64)
// ===========================================================================
#define TS 64
#define FBK 16
__global__ __launch_bounds__(256)
void k_gemm_splitk(const float* __restrict__ A, const float* __restrict__ W,
                   float* __restrict__ Part, int M, int Nn, int K, int klen)
{
    __shared__ float As[FBK][TS];
    __shared__ float Ws[FBK][TS];
    const int tx = threadIdx.x, ty = threadIdx.y;
    const int t  = ty * 16 + tx;
    const int n0 = blockIdx.x * TS;
    const int kb = blockIdx.z * klen;
    const int alm = t >> 2, alk = (t & 3) * 4;
    const int wr  = t >> 4, wc  = (t & 15) * 4;
    float acc[4][4] = {};
    for (int k0 = kb; k0 < kb + klen; k0 += FBK) {
        float4 av = *(const float4*)(A + (size_t)alm * K + k0 + alk);
        As[alk + 0][alm] = av.x; As[alk + 1][alm] = av.y;
        As[alk + 2][alm] = av.z; As[alk + 3][alm] = av.w;
        *(float4*)(&Ws[wr][wc]) = *(const float4*)(W + (size_t)(k0 + wr) * Nn + n0 + wc);
        __syncthreads();
        #pragma unroll
        for (int k = 0; k < FBK; ++k) {
            float a[4], w2[4];
            #pragma unroll
            for (int q = 0; q < 4; ++q) { a[q] = As[k][ty * 4 + q]; w2[q] = Ws[k][tx * 4 + q]; }
            #pragma unroll
            for (int ii = 0; ii < 4; ++ii)
                #pragma unroll
                for (int jj = 0; jj < 4; ++jj)
                    acc[ii][jj] = fmaf(a[ii], w2[jj], acc[ii][jj]);
        }
        __syncthreads();
    }
    float* Pb = Part + (size_t)blockIdx.z * M * Nn;
    #pragma unroll
    for (int ii = 0; ii < 4; ++ii) {
        const int m = ty * 4 + ii;
        #pragma unroll
        for (int jj = 0; jj < 4; ++jj)
            Pb[(size_t)m * Nn + n0 + tx * 4 + jj] = acc[ii][jj];
    }
}

template<int ACT>
__global__ __launch_bounds__(256)
void k_reduce_bias_act(const float* __restrict__ Part, const float* __restrict__ bias,
                       float* __restrict__ C, int MN, int Nn, int SK)
{
    const int i = blockIdx.x * 256 + threadIdx.x;
    if (i < MN) {
        float s = 0.0f;
        for (int k = 0; k < SK; ++k) s += Part[(size_t)k * MN + i];
        float v = s + bias[i % Nn];
        if (ACT) v = silu_f(v);
        C[i] = v;
    }
}

__global__ __launch_bounds__(256)
void k_rownorm(float* __restrict__ f)
{
    __shared__ float red[256];
    const int b = blockIdx.x, t = threadIdx.x;
    float ss = 0.0f;
    for (int c = t; c < HID_; c += 256) {
        const float v = f[(size_t)b * HID_ + c];
        ss += v * v;
    }
    red[t] = ss;
    __syncthreads();
    for (int o = 128; o > 0; o >>= 1) {
        if (t < o) red[t] += red[t + o];
        __syncthreads();
    }
    const float inv = 1.0f / fmaxf(sqrtf(red[0]), 1e-12f);
    for (int c = t; c < HID_; c += 256)
        f[(size_t)b * HID_ + c] *= inv;
}

// ===========================================================================
extern "C" void kernel_launch(void* const* d_in, const int* in_sizes, int n_in,
                              void* d_out, int out_size, void* d_ws, size_t ws_size,
                              hipStream_t stream)
{
    const float* node = (const float*)d_in[0];
    const int*   adj  = (const int*)d_in[1];
    const float* Wv_w = (const float*)d_in[3];  const float* Wv_b = (const float*)d_in[4];
    const float* Ww_w = (const float*)d_in[5];  const float* Ww_b = (const float*)d_in[6];
    const float* Wg_w = (const float*)d_in[7];  const float* Wg_b = (const float*)d_in[8];
    const float* W0 = (const float*)d_in[9];    const float* b0 = (const float*)d_in[10];
    const float* W1 = (const float*)d_in[11];   const float* b1 = (const float*)d_in[12];
    const float* W2 = (const float*)d_in[13];   const float* b2 = (const float*)d_in[14];
    const float* W3 = (const float*)d_in[15];   const float* b3 = (const float*)d_in[16];
    float* out = (float*)d_out;

    float* ws = (float*)d_ws;
    const size_t SZ = (size_t)B_ * N_ * R_;              // 8,388,608 elems
    float* S     = ws;                                   // B*N*N fp32 (walk loop)
    float* h0    = ws;                                   // alias S (post-loop)
    float* h1    = ws + 98304;
    float* h2    = ws + 196608;
    float* Part  = ws + 262144;                          // 16*98304 floats (in S region)
    float* mj    = ws + (size_t)B_ * N_ * N_;            // 32768
    float* invD  = mj + 32768;
    float* f     = invD + 32768;                         // 98304
    u16* u0   = (u16*)(f + 98304);
    u16* F1h  = u0;            u16* F1l  = F1h + SZ;
    u16* X1h  = F1l + SZ;      u16* X1l  = X1h + SZ;
    u16* X2h  = X1l + SZ;      u16* X2l  = X2h + SZ;
    u16* XTh  = X2l + SZ;      u16* XTl  = XTh + SZ;
    u16* Ph   = XTl + SZ;      u16* Pl   = Ph + SZ;
    u16* WvTh = Pl + SZ;       u16* WvTl = WvTh + 65536;
    u16* WwTh = WvTl + 65536;  u16* WwTl = WwTh + 65536;
    u16* WgTh = WwTl + 65536;  u16* WgTl = WgTh + 65536;
    u8*  msk  = (u8*)(WgTl + 65536);

    // --- one-time conversions ---
    k_cvt_wT<<<256, 256, 0, stream>>>(Wv_w, WvTh, WvTl, 256, 256);
    k_cvt_wT<<<256, 256, 0, stream>>>(Ww_w, WwTh, WwTl, 256, 256);
    k_cvt_wT<<<256, 256, 0, stream>>>(Wg_w, WgTh, WgTl, 256, 256);
    k_adj_mask<<<16384, 256, 0, stream>>>(adj, msk, B_ * N_ * N_ / 4);
    (void)hipMemsetAsync(f, 0, 98304 * sizeof(float), stream);

    // --- F1 = silu(node @ Wv + b)  (A = fp32 node, on-the-fly split) ---
    k_mf_gemm<1, 1><<<dim3(2, 256), 256, 0, stream>>>(
        node, nullptr, nullptr, WvTh, WvTl, Wv_b, F1h, F1l, B_ * N_, R_, 256);
    k_mf_wg<<<dim3(2, 256), 256, 0, stream>>>(F1h, F1l, WgTh, WgTl, Wg_b, f, 0);
    k_transpose_bf2<<<dim3(4, 8, 128), 256, 0, stream>>>(F1h, F1l, XTh, XTl);

    const u16 *Xh = F1h, *Xl = F1l;
    u16 *Yh = X1h, *Yl = X1l;
    for (int step = 1; step < L_; ++step) {
        k_mf_gemm<0, 0><<<dim3(2, 256), 256, 0, stream>>>(
            nullptr, Xh, Xl, WwTh, WwTl, Ww_b, Ph, Pl, B_ * N_, R_, 256);
        k_mf_abt<<<dim3(4, 4, 64), 256, 0, stream>>>(Ph, Pl, Xh, Xl, msk, S);
        k_colstats<<<512, 256, 0, stream>>>(S, mj, invD);
        k_mf_af<<<dim3(2, 4, 64), 256, 0, stream>>>(
            S, mj, invD, XTh, XTl, Xh, Xl, F1h, F1l, Yh, Yl);
        k_mf_wg<<<dim3(2, 256), 256, 0, stream>>>(Yh, Yl, WgTh, WgTl, Wg_b, f, step);
        if (step < L_ - 1)
            k_transpose_bf2<<<dim3(4, 8, 128), 256, 0, stream>>>(Yh, Yl, XTh, XTl);
        const u16 *nxh = Yh, *nxl = Yl;
        if (step == 1) { Yh = X2h; Yl = X2l; }
        else           { Yh = (u16*)Xh; Yl = (u16*)Xl; }
        Xh = nxh; Xl = nxl;
    }

    k_rownorm<<<B_, 256, 0, stream>>>(f);

    // --- MLP head (fp32 split-K): 1536 -> 1536 -> 768 -> 128 ---
    const dim3 fblk(16, 16);
    k_gemm_splitk<<<dim3(24, 1, 16), fblk, 0, stream>>>(f,  W0, Part, B_, HID_, HID_, 96);
    k_reduce_bias_act<1><<<384, 256, 0, stream>>>(Part, b0, h0, B_ * HID_, HID_, 16);
    k_gemm_splitk<<<dim3(24, 1, 16), fblk, 0, stream>>>(h0, W1, Part, B_, HID_, HID_, 96);
    k_reduce_bias_act<1><<<384, 256, 0, stream>>>(Part, b1, h1, B_ * HID_, HID_, 16);
    k_gemm_splitk<<<dim3(12, 1, 16), fblk, 0, stream>>>(h1, W2, Part, B_, 768, HID_, 96);
    k_reduce_bias_act<1><<<192, 256, 0, stream>>>(Part, b2, h2, B_ * 768, 768, 16);
    k_gemm_splitk<<<dim3(2, 1, 8),   fblk, 0, stream>>>(h2, W3, Part, B_, 128, 768, 96);
    k_reduce_bias_act<0><<<32, 256, 0, stream>>>(Part, b3, out, B_ * 128, 128, 8);
}

// Round 11
// 978.255 us; speedup vs baseline: 2.8623x; 1.0630x over previous
//
#include <hip/hip_runtime.h>

#define B_   64
#define N_   512
#define R_   256
#define L_   6
#define HID_ 1536

#define BM 128
#define BN 128
#define BK 32
#define LDT 40   // padded LDS stride (u16 elems); 2-way bank alias only = free

typedef __attribute__((ext_vector_type(4))) float f32x4;
typedef __attribute__((ext_vector_type(8))) __bf16 bf16x8;
typedef __attribute__((ext_vector_type(8))) unsigned short u16x8;
typedef unsigned short u16;
typedef unsigned char  u8;
typedef unsigned int   u32;

__device__ __forceinline__ float silu_f(float x) { return x / (1.0f + __expf(-x)); }

__device__ __forceinline__ float bf2f(u16 h) {
    u32 u = ((u32)h) << 16;
    return __builtin_bit_cast(float, u);
}
// truncation split: x ~= hi + lo with ~17 effective mantissa bits
__device__ __forceinline__ void split2(float x, u16& h, u16& l) {
    u32 u = __builtin_bit_cast(u32, x);
    h = (u16)(u >> 16);
    float r = x - __builtin_bit_cast(float, u & 0xffff0000u);   // exact
    l = (u16)(__builtin_bit_cast(u32, r) >> 16);
}
__device__ __forceinline__ float join2(u16 h, u16 l) {
    return bf2f(h) + bf2f(l);
}

// ===========================================================================
// Split-GEMM core helper: ACC += Ah*Bh + Al*Bh + Ah*Bl
// ===========================================================================
#define MFMA_TRIPLE(ACC, Ash, Asl, Bsh, Bsl)                                    \
    {                                                                           \
        const int k8 = (lane >> 4) * 8, cl = lane & 15;                         \
        bf16x8 bh[4], bl[4];                                                    \
        _Pragma("unroll")                                                       \
        for (int n = 0; n < 4; ++n) {                                           \
            bh[n] = *(const bf16x8*)&Bsh[(wc * 64 + n * 16 + cl) * LDT + k8];   \
            bl[n] = *(const bf16x8*)&Bsl[(wc * 64 + n * 16 + cl) * LDT + k8];   \
        }                                                                       \
        _Pragma("unroll")                                                       \
        for (int m = 0; m < 4; ++m) {                                           \
            bf16x8 ah = *(const bf16x8*)&Ash[(wr * 64 + m * 16 + cl) * LDT + k8]; \
            bf16x8 al = *(const bf16x8*)&Asl[(wr * 64 + m * 16 + cl) * LDT + k8]; \
            _Pragma("unroll")                                                   \
            for (int n = 0; n < 4; ++n) {                                       \
                ACC[m][n] = __builtin_amdgcn_mfma_f32_16x16x32_bf16(ah, bh[n], ACC[m][n], 0, 0, 0); \
                ACC[m][n] = __builtin_amdgcn_mfma_f32_16x16x32_bf16(al, bh[n], ACC[m][n], 0, 0, 0); \
                ACC[m][n] = __builtin_amdgcn_mfma_f32_16x16x32_bf16(ah, bl[n], ACC[m][n], 0, 0, 0); \
            }                                                                   \
        }                                                                       \
    }

#define STAGE2(DSTH, DSTL, SRCH, SRCL)                                          \
    {                                                                           \
        *(u16x8*)&DSTH[sr * LDT + sc]     = *(const u16x8*)(SRCH);              \
        *(u16x8*)&DSTH[sr * LDT + sc + 8] = *(const u16x8*)(SRCH + 8);          \
        *(u16x8*)&DSTL[sr * LDT + sc]     = *(const u16x8*)(SRCL);              \
        *(u16x8*)&DSTL[sr * LDT + sc + 8] = *(const u16x8*)(SRCL + 8);          \
    }

// ===========================================================================
// C = act(A @ W + bias), A: fp32 (AFP32=1, on-the-fly split) or hi/lo pair.
// W pre-split as WT[Nn,K] hi/lo. Output written as hi/lo pair.
// ===========================================================================
template<int ACT, int AFP32>
__global__ __launch_bounds__(256)
void k_mf_gemm(const float* __restrict__ Af,
               const u16* __restrict__ Ah, const u16* __restrict__ Al,
               const u16* __restrict__ WTh, const u16* __restrict__ WTl,
               const float* __restrict__ bias,
               u16* __restrict__ Ch, u16* __restrict__ Cl,
               int M, int Nn, int K)
{
    __shared__ u16 Ash[BM * LDT], Asl[BM * LDT];
    __shared__ u16 Bsh[BN * LDT], Bsl[BN * LDT];
    const int t = threadIdx.x, lane = t & 63, w = t >> 6;
    const int wr = w >> 1, wc = w & 1;
    const int m0 = blockIdx.y * BM, n0 = blockIdx.x * BN;
    const int sr = t >> 1, sc = (t & 1) * 16;
    f32x4 acc[4][4] = {};
    for (int k0 = 0; k0 < K; k0 += BK) {
        if (AFP32) {
            const float* ga = Af + (size_t)(m0 + sr) * K + k0 + sc;
            u16x8 vh0, vl0, vh1, vl1;
            #pragma unroll
            for (int p = 0; p < 2; ++p) {
                const float4 a = *(const float4*)(ga + p * 8);
                const float4 b = *(const float4*)(ga + p * 8 + 4);
                u16 h, l;
                split2(a.x, h, l); (p ? vh1 : vh0)[0] = h; (p ? vl1 : vl0)[0] = l;
                split2(a.y, h, l); (p ? vh1 : vh0)[1] = h; (p ? vl1 : vl0)[1] = l;
                split2(a.z, h, l); (p ? vh1 : vh0)[2] = h; (p ? vl1 : vl0)[2] = l;
                split2(a.w, h, l); (p ? vh1 : vh0)[3] = h; (p ? vl1 : vl0)[3] = l;
                split2(b.x, h, l); (p ? vh1 : vh0)[4] = h; (p ? vl1 : vl0)[4] = l;
                split2(b.y, h, l); (p ? vh1 : vh0)[5] = h; (p ? vl1 : vl0)[5] = l;
                split2(b.z, h, l); (p ? vh1 : vh0)[6] = h; (p ? vl1 : vl0)[6] = l;
                split2(b.w, h, l); (p ? vh1 : vh0)[7] = h; (p ? vl1 : vl0)[7] = l;
            }
            *(u16x8*)&Ash[sr * LDT + sc]     = vh0;
            *(u16x8*)&Ash[sr * LDT + sc + 8] = vh1;
            *(u16x8*)&Asl[sr * LDT + sc]     = vl0;
            *(u16x8*)&Asl[sr * LDT + sc + 8] = vl1;
        } else {
            const u16* gah = Ah + (size_t)(m0 + sr) * K + k0 + sc;
            const u16* gal = Al + (size_t)(m0 + sr) * K + k0 + sc;
            STAGE2(Ash, Asl, gah, gal)
        }
        const u16* gbh = WTh + (size_t)(n0 + sr) * K + k0 + sc;
        const u16* gbl = WTl + (size_t)(n0 + sr) * K + k0 + sc;
        STAGE2(Bsh, Bsl, gbh, gbl)
        __syncthreads();
        MFMA_TRIPLE(acc, Ash, Asl, Bsh, Bsl)
        __syncthreads();
    }
    const int cl = lane & 15, rh = lane >> 4;
    #pragma unroll
    for (int m = 0; m < 4; ++m)
        #pragma unroll
        for (int n = 0; n < 4; ++n) {
            const int col = n0 + wc * 64 + n * 16 + cl;
            const float bb = bias[col];
            #pragma unroll
            for (int q = 0; q < 4; ++q) {
                const int row = m0 + wr * 64 + m * 16 + rh * 4 + q;
                float v = acc[m][n][q] + bb;
                if (ACT) v = silu_f(v);
                const size_t idx = (size_t)row * Nn + col;
                split2(v, Ch[idx], Cl[idx]);
            }
        }
}

// ===========================================================================
// Fused: P = X @ Ww + bw (if DO_P), and f[b,step*R+n] += sum_rows silu(X@Wg+bg)
// Shares the A staging between both GEMMs. Grid (2 n-tiles, 256 m-tiles).
// ===========================================================================
template<int DO_P>
__global__ __launch_bounds__(256)
void k_mf_pw(const u16* __restrict__ Xh, const u16* __restrict__ Xl,
             const u16* __restrict__ WwTh, const u16* __restrict__ WwTl,
             const u16* __restrict__ WgTh, const u16* __restrict__ WgTl,
             const float* __restrict__ bw, const float* __restrict__ bg,
             u16* __restrict__ Ph, u16* __restrict__ Pl,
             float* __restrict__ f, int step)
{
    __shared__ u16 Ash[BM * LDT], Asl[BM * LDT];
    __shared__ u16 Bwh[BN * LDT], Bwl[BN * LDT];
    __shared__ u16 Bgh[BN * LDT], Bgl[BN * LDT];
    const int t = threadIdx.x, lane = t & 63, w = t >> 6;
    const int wr = w >> 1, wc = w & 1;
    const int m0 = blockIdx.y * BM, n0 = blockIdx.x * BN;
    const int sr = t >> 1, sc = (t & 1) * 16;
    f32x4 accp[4][4] = {};
    f32x4 accg[4][4] = {};
    for (int k0 = 0; k0 < R_; k0 += BK) {
        const u16* gah = Xh + (size_t)(m0 + sr) * R_ + k0 + sc;
        const u16* gal = Xl + (size_t)(m0 + sr) * R_ + k0 + sc;
        STAGE2(Ash, Asl, gah, gal)
        if (DO_P) {
            const u16* gwh = WwTh + (size_t)(n0 + sr) * R_ + k0 + sc;
            const u16* gwl = WwTl + (size_t)(n0 + sr) * R_ + k0 + sc;
            STAGE2(Bwh, Bwl, gwh, gwl)
        }
        const u16* ggh = WgTh + (size_t)(n0 + sr) * R_ + k0 + sc;
        const u16* ggl = WgTl + (size_t)(n0 + sr) * R_ + k0 + sc;
        STAGE2(Bgh, Bgl, ggh, ggl)
        __syncthreads();
        if (DO_P) { MFMA_TRIPLE(accp, Ash, Asl, Bwh, Bwl) }
        MFMA_TRIPLE(accg, Ash, Asl, Bgh, Bgl)
        __syncthreads();
    }
    const int cl = lane & 15, rh = lane >> 4;
    const int bb = blockIdx.y >> 2;              // 4 m-tiles of 128 per batch
    #pragma unroll
    for (int n = 0; n < 4; ++n) {
        const int col = n0 + wc * 64 + n * 16 + cl;
        const float bias = bg[col];
        float s = 0.0f;
        #pragma unroll
        for (int m = 0; m < 4; ++m)
            #pragma unroll
            for (int q = 0; q < 4; ++q)
                s += silu_f(accg[m][n][q] + bias);
        s += __shfl_xor(s, 16);
        s += __shfl_xor(s, 32);
        if (rh == 0)
            atomicAdd(&f[(size_t)bb * HID_ + step * R_ + col], s);
    }
    if (DO_P) {
        #pragma unroll
        for (int m = 0; m < 4; ++m)
            #pragma unroll
            for (int n = 0; n < 4; ++n) {
                const int col = n0 + wc * 64 + n * 16 + cl;
                const float bwv = bw[col];
                #pragma unroll
                for (int q = 0; q < 4; ++q) {
                    const int row = m0 + wr * 64 + m * 16 + rh * 4 + q;
                    const size_t idx = (size_t)row * R_ + col;
                    split2(accp[m][n][q] + bwv, Ph[idx], Pl[idx]);
                }
            }
    }
}

// ===========================================================================
// S[b,i,j] = sum_r P[b,i,r]*Fn[b,j,r], masked by u8 msk -> fp32
// Grid (64 b, 4 j-tiles, 4 i-tiles): same-b blocks ≡ b (mod 8) -> same XCD L2
// ===========================================================================
__global__ __launch_bounds__(256)
void k_mf_abt(const u16* __restrict__ Ph, const u16* __restrict__ Pl,
              const u16* __restrict__ Fh, const u16* __restrict__ Fl,
              const u8* __restrict__ msk, float* __restrict__ S)
{
    __shared__ u16 Ash[BM * LDT], Asl[BM * LDT];
    __shared__ u16 Bsh[BN * LDT], Bsl[BN * LDT];
    const int t = threadIdx.x, lane = t & 63, w = t >> 6;
    const int wr = w >> 1, wc = w & 1;
    const int b = blockIdx.x;
    const int j0 = blockIdx.y * BN, i0 = blockIdx.z * BM;
    const size_t boff = (size_t)b * N_ * R_;
    const int sr = t >> 1, sc = (t & 1) * 16;
    f32x4 acc[4][4] = {};
    for (int k0 = 0; k0 < R_; k0 += BK) {
        const u16* gah = Ph + boff + (size_t)(i0 + sr) * R_ + k0 + sc;
        const u16* gal = Pl + boff + (size_t)(i0 + sr) * R_ + k0 + sc;
        STAGE2(Ash, Asl, gah, gal)
        const u16* gbh = Fh + boff + (size_t)(j0 + sr) * R_ + k0 + sc;
        const u16* gbl = Fl + boff + (size_t)(j0 + sr) * R_ + k0 + sc;
        STAGE2(Bsh, Bsl, gbh, gbl)
        __syncthreads();
        MFMA_TRIPLE(acc, Ash, Asl, Bsh, Bsl)
        __syncthreads();
    }
    const int cl = lane & 15, rh = lane >> 4;
    const u8*   mb = msk + (size_t)b * N_ * N_;
    float*      Sb = S   + (size_t)b * N_ * N_;
    #pragma unroll
    for (int m = 0; m < 4; ++m)
        #pragma unroll
        for (int n = 0; n < 4; ++n)
            #pragma unroll
            for (int q = 0; q < 4; ++q) {
                const int row = i0 + wr * 64 + m * 16 + rh * 4 + q;
                const int col = j0 + wc * 64 + n * 16 + cl;
                const size_t idx = (size_t)row * N_ + col;
                Sb[idx] = mb[idx] ? acc[m][n][q] : -1.0e8f;
            }
}

// ===========================================================================
// Column stats over axis i: m_j, invD_j  (fp32)
// ===========================================================================
__global__ __launch_bounds__(256)
void k_colstats(const float* __restrict__ S, float* __restrict__ mj,
                float* __restrict__ invD)
{
    __shared__ float lm[4][64], ls[4][64];
    const int t = threadIdx.x;
    const int q = t >> 6, c = t & 63;
    const int b = blockIdx.x >> 3;
    const int j = (blockIdx.x & 7) * 64 + c;
    const float* Sb = S + (size_t)b * N_ * N_ + j;
    float m = -3.0e38f, s = 0.0f;
    for (int i = q * 128; i < q * 128 + 128; ++i) {
        const float v = Sb[(size_t)i * N_];
        const float nm = fmaxf(m, v);
        s = s * __expf(m - nm) + __expf(v - nm);
        m = nm;
    }
    lm[q][c] = m; ls[q][c] = s;
    __syncthreads();
    if (q == 0) {
        float M = lm[0][c];
        #pragma unroll
        for (int k = 1; k < 4; ++k) M = fmaxf(M, lm[k][c]);
        float D = 0.0f;
        #pragma unroll
        for (int k = 0; k < 4; ++k) D += ls[k][c] * __expf(lm[k][c] - M);
        mj[(size_t)b * N_ + j]   = M;
        invD[(size_t)b * N_ + j] = 1.0f / D;
    }
}

// ===========================================================================
// Out = (Fn + softmax(S) @ Fn) * F1 ; A staged from fp32 S (exp-normalized,
// split hi/lo), B = FT hi/lo; output split hi/lo
// Grid (64 b, 2 r-tiles, 4 i-tiles): same-b blocks on same XCD L2
// ===========================================================================
__global__ __launch_bounds__(256)
void k_mf_af(const float* __restrict__ S, const float* __restrict__ mj,
             const float* __restrict__ invD,
             const u16* __restrict__ FTh, const u16* __restrict__ FTl,
             const u16* __restrict__ Fh, const u16* __restrict__ Fl,
             const u16* __restrict__ F1h, const u16* __restrict__ F1l,
             u16* __restrict__ Oh, u16* __restrict__ Ol)
{
    __shared__ u16 Ash[BM * LDT], Asl[BM * LDT];
    __shared__ u16 Bsh[BN * LDT], Bsl[BN * LDT];
    const int t = threadIdx.x, lane = t & 63, w = t >> 6;
    const int wr = w >> 1, wc = w & 1;
    const int b = blockIdx.x;
    const int r0 = blockIdx.y * BN, i0 = blockIdx.z * BM;
    const float* Sb  = S    + (size_t)b * N_ * N_;
    const float* mb  = mj   + (size_t)b * N_;
    const float* db  = invD + (size_t)b * N_;
    const size_t tboff = (size_t)b * R_ * N_;
    const int sr = t >> 1, sc = (t & 1) * 16;
    f32x4 acc[4][4] = {};
    for (int k0 = 0; k0 < N_; k0 += BK) {          // k = j
        const float* gs = Sb + (size_t)(i0 + sr) * N_ + k0 + sc;
        const float* gm = mb + k0 + sc;
        const float* gd = db + k0 + sc;
        #pragma unroll
        for (int h = 0; h < 2; ++h) {
            u16x8 vh, vl;
            #pragma unroll
            for (int p4 = 0; p4 < 2; ++p4) {
                const float4 sv = *(const float4*)(gs + h * 8 + p4 * 4);
                const float4 mv = *(const float4*)(gm + h * 8 + p4 * 4);
                const float4 dv = *(const float4*)(gd + h * 8 + p4 * 4);
                u16 th, tl;
                split2(__expf(sv.x - mv.x) * dv.x, th, tl); vh[p4 * 4 + 0] = th; vl[p4 * 4 + 0] = tl;
                split2(__expf(sv.y - mv.y) * dv.y, th, tl); vh[p4 * 4 + 1] = th; vl[p4 * 4 + 1] = tl;
                split2(__expf(sv.z - mv.z) * dv.z, th, tl); vh[p4 * 4 + 2] = th; vl[p4 * 4 + 2] = tl;
                split2(__expf(sv.w - mv.w) * dv.w, th, tl); vh[p4 * 4 + 3] = th; vl[p4 * 4 + 3] = tl;
            }
            *(u16x8*)&Ash[sr * LDT + sc + h * 8] = vh;
            *(u16x8*)&Asl[sr * LDT + sc + h * 8] = vl;
        }
        const u16* gbh = FTh + tboff + (size_t)(r0 + sr) * N_ + k0 + sc;
        const u16* gbl = FTl + tboff + (size_t)(r0 + sr) * N_ + k0 + sc;
        STAGE2(Bsh, Bsl, gbh, gbl)
        __syncthreads();
        MFMA_TRIPLE(acc, Ash, Asl, Bsh, Bsl)
        __syncthreads();
    }
    const int cl = lane & 15, rh = lane >> 4;
    #pragma unroll
    for (int m = 0; m < 4; ++m)
        #pragma unroll
        for (int n = 0; n < 4; ++n)
            #pragma unroll
            for (int q = 0; q < 4; ++q) {
                const int row = i0 + wr * 64 + m * 16 + rh * 4 + q;
                const int col = r0 + wc * 64 + n * 16 + cl;
                const size_t idx = ((size_t)b * N_ + row) * R_ + col;
                const float fn = join2(Fh[idx], Fl[idx]);
                const float f1 = join2(F1h[idx], F1l[idx]);
                split2((fn + acc[m][n][q]) * f1, Oh[idx], Ol[idx]);
            }
}

// ===========================================================================
// u16 plane transpose, both planes in one launch (z bit selects plane):
// FT[b,r,i] = Fn[b,i,r]
// ===========================================================================
#define TLD 72
__global__ __launch_bounds__(256)
void k_transpose_bf2(const u16* __restrict__ F0, const u16* __restrict__ F1p,
                     u16* __restrict__ T0, u16* __restrict__ T1p)
{
    __shared__ u16 tile[64 * TLD];
    const int pl = blockIdx.z & 1;
    const int b  = blockIdx.z >> 1;
    const u16* Fn = pl ? F1p : F0;
    u16*       FT = pl ? T1p : T0;
    const int i0 = blockIdx.y * 64;
    const int r0 = blockIdx.x * 64;
    const u16* src = Fn + ((size_t)b * N_ + i0) * R_ + r0;
    u16*       dst = FT + ((size_t)b * R_ + r0) * N_ + i0;
    const int t = threadIdx.x;
    const int rr = t >> 2, cc = (t & 3) * 16;
    *(u16x8*)&tile[rr * TLD + cc]     = *(const u16x8*)(src + (size_t)rr * R_ + cc);
    *(u16x8*)&tile[rr * TLD + cc + 8] = *(const u16x8*)(src + (size_t)rr * R_ + cc + 8);
    __syncthreads();
    const int ro = t >> 2, co = (t & 3) * 16;
    u16x8 v0, v1;
    #pragma unroll
    for (int q = 0; q < 8; ++q) v0[q] = tile[(co + q) * TLD + ro];
    #pragma unroll
    for (int q = 0; q < 8; ++q) v1[q] = tile[(co + 8 + q) * TLD + ro];
    *(u16x8*)(dst + (size_t)ro * N_ + co)     = v0;
    *(u16x8*)(dst + (size_t)ro * N_ + co + 8) = v1;
}

// WT[n,k] hi/lo = split(W[k,n])
__global__ __launch_bounds__(256)
void k_cvt_wT(const float* __restrict__ Win, u16* __restrict__ WTh,
              u16* __restrict__ WTl, int K, int Nn)
{
    const int idx = blockIdx.x * 256 + threadIdx.x;
    if (idx < K * Nn) {
        const int n = idx / K, k = idx % K;
        split2(Win[(size_t)k * Nn + n], WTh[idx], WTl[idx]);
    }
}

// adj int32 -> u8 mask (4 elems/thread)
__global__ __launch_bounds__(256)
void k_adj_mask(const int* __restrict__ adj, u8* __restrict__ msk, int n4)
{
    const int i = blockIdx.x * 256 + threadIdx.x;
    if (i < n4) {
        const int4 a = *(const int4*)(adj + (size_t)i * 4);
        uchar4 m;
        m.x = a.x ? 1 : 0; m.y = a.y ? 1 : 0;
        m.z = a.z ? 1 : 0; m.w = a.w ? 1 : 0;
        *(uchar4*)(msk + (size_t)i * 4) = m;
    }
}

// ===========================================================================
// Split-K fp32 GEMM + reduce for the thin MLP head (M=64)
// ===========================================================================
#define TS 64
#define FBK 16
__global__ __launch_bounds__(256)
void k_gemm_splitk(const float* __restrict__ A, const float* __restrict__ W,
                   float* __restrict__ Part, int M, int Nn, int K, int klen)
{
    __shared__ float As[FBK][TS];
    __shared__ float Ws[FBK][TS];
    const int tx = threadIdx.x, ty = threadIdx.y;
    const int t  = ty * 16 + tx;
    const int n0 = blockIdx.x * TS;
    const int kb = blockIdx.z * klen;
    const int alm = t >> 2, alk = (t & 3) * 4;
    const int wr  = t >> 4, wc  = (t & 15) * 4;
    float acc[4][4] = {};
    for (int k0 = kb; k0 < kb + klen; k0 += FBK) {
        float4 av = *(const float4*)(A + (size_t)alm * K + k0 + alk);
        As[alk + 0][alm] = av.x; As[alk + 1][alm] = av.y;
        As[alk + 2][alm] = av.z; As[alk + 3][alm] = av.w;
        *(float4*)(&Ws[wr][wc]) = *(const float4*)(W + (size_t)(k0 + wr) * Nn + n0 + wc);
        __syncthreads();
        #pragma unroll
        for (int k = 0; k < FBK; ++k) {
            float a[4], w2[4];
            #pragma unroll
            for (int q = 0; q < 4; ++q) { a[q] = As[k][ty * 4 + q]; w2[q] = Ws[k][tx * 4 + q]; }
            #pragma unroll
            for (int ii = 0; ii < 4; ++ii)
                #pragma unroll
                for (int jj = 0; jj < 4; ++jj)
                    acc[ii][jj] = fmaf(a[ii], w2[jj], acc[ii][jj]);
        }
        __syncthreads();
    }
    float* Pb = Part + (size_t)blockIdx.z * M * Nn;
    #pragma unroll
    for (int ii = 0; ii < 4; ++ii) {
        const int m = ty * 4 + ii;
        #pragma unroll
        for (int jj = 0; jj < 4; ++jj)
            Pb[(size_t)m * Nn + n0 + tx * 4 + jj] = acc[ii][jj];
    }
}

template<int ACT>
__global__ __launch_bounds__(256)
void k_reduce_bias_act(const float* __restrict__ Part, const float* __restrict__ bias,
                       float* __restrict__ C, int MN, int Nn, int SK)
{
    const int i = blockIdx.x * 256 + threadIdx.x;
    if (i < MN) {
        float s = 0.0f;
        for (int k = 0; k < SK; ++k) s += Part[(size_t)k * MN + i];
        float v = s + bias[i % Nn];
        if (ACT) v = silu_f(v);
        C[i] = v;
    }
}

__global__ __launch_bounds__(256)
void k_rownorm(float* __restrict__ f)
{
    __shared__ float red[256];
    const int b = blockIdx.x, t = threadIdx.x;
    float ss = 0.0f;
    for (int c = t; c < HID_; c += 256) {
        const float v = f[(size_t)b * HID_ + c];
        ss += v * v;
    }
    red[t] = ss;
    __syncthreads();
    for (int o = 128; o > 0; o >>= 1) {
        if (t < o) red[t] += red[t + o];
        __syncthreads();
    }
    const float inv = 1.0f / fmaxf(sqrtf(red[0]), 1e-12f);
    for (int c = t; c < HID_; c += 256)
        f[(size_t)b * HID_ + c] *= inv;
}

// ===========================================================================
extern "C" void kernel_launch(void* const* d_in, const int* in_sizes, int n_in,
                              void* d_out, int out_size, void* d_ws, size_t ws_size,
                              hipStream_t stream)
{
    const float* node = (const float*)d_in[0];
    const int*   adj  = (const int*)d_in[1];
    const float* Wv_w = (const float*)d_in[3];  const float* Wv_b = (const float*)d_in[4];
    const float* Ww_w = (const float*)d_in[5];  const float* Ww_b = (const float*)d_in[6];
    const float* Wg_w = (const float*)d_in[7];  const float* Wg_b = (const float*)d_in[8];
    const float* W0 = (const float*)d_in[9];    const float* b0 = (const float*)d_in[10];
    const float* W1 = (const float*)d_in[11];   const float* b1 = (const float*)d_in[12];
    const float* W2 = (const float*)d_in[13];   const float* b2 = (const float*)d_in[14];
    const float* W3 = (const float*)d_in[15];   const float* b3 = (const float*)d_in[16];
    float* out = (float*)d_out;

    float* ws = (float*)d_ws;
    const size_t SZ = (size_t)B_ * N_ * R_;              // 8,388,608 elems
    float* S     = ws;                                   // B*N*N fp32 (walk loop)
    float* h0    = ws;                                   // alias S (post-loop)
    float* h1    = ws + 98304;
    float* h2    = ws + 196608;
    float* Part  = ws + 262144;                          // 16*98304 floats (in S region)
    float* mj    = ws + (size_t)B_ * N_ * N_;            // 32768
    float* invD  = mj + 32768;
    float* f     = invD + 32768;                         // 98304
    u16* u0   = (u16*)(f + 98304);
    u16* F1h  = u0;            u16* F1l  = F1h + SZ;
    u16* X1h  = F1l + SZ;      u16* X1l  = X1h + SZ;
    u16* X2h  = X1l + SZ;      u16* X2l  = X2h + SZ;
    u16* XTh  = X2l + SZ;      u16* XTl  = XTh + SZ;
    u16* Ph   = XTl + SZ;      u16* Pl   = Ph + SZ;
    u16* WvTh = Pl + SZ;       u16* WvTl = WvTh + 65536;
    u16* WwTh = WvTl + 65536;  u16* WwTl = WwTh + 65536;
    u16* WgTh = WwTl + 65536;  u16* WgTl = WgTh + 65536;
    u8*  msk  = (u8*)(WgTl + 65536);

    // --- one-time conversions ---
    k_cvt_wT<<<256, 256, 0, stream>>>(Wv_w, WvTh, WvTl, 256, 256);
    k_cvt_wT<<<256, 256, 0, stream>>>(Ww_w, WwTh, WwTl, 256, 256);
    k_cvt_wT<<<256, 256, 0, stream>>>(Wg_w, WgTh, WgTl, 256, 256);
    k_adj_mask<<<16384, 256, 0, stream>>>(adj, msk, B_ * N_ * N_ / 4);
    (void)hipMemsetAsync(f, 0, 98304 * sizeof(float), stream);

    // --- F1 = silu(node @ Wv + b)  (A = fp32 node, on-the-fly split) ---
    k_mf_gemm<1, 1><<<dim3(2, 256), 256, 0, stream>>>(
        node, nullptr, nullptr, WvTh, WvTl, Wv_b, F1h, F1l, B_ * N_, R_, 256);
    // fused: f[0] rowsum + P_1 = F1 @ Ww + b
    k_mf_pw<1><<<dim3(2, 256), 256, 0, stream>>>(
        F1h, F1l, WwTh, WwTl, WgTh, WgTl, Ww_b, Wg_b, Ph, Pl, f, 0);
    k_transpose_bf2<<<dim3(4, 8, 128), 256, 0, stream>>>(F1h, F1l, XTh, XTl);

    const u16 *Xh = F1h, *Xl = F1l;
    u16 *Yh = X1h, *Yl = X1l;
    for (int step = 1; step < L_; ++step) {
        k_mf_abt<<<dim3(64, 4, 4), 256, 0, stream>>>(Ph, Pl, Xh, Xl, msk, S);
        k_colstats<<<512, 256, 0, stream>>>(S, mj, invD);
        k_mf_af<<<dim3(64, 2, 4), 256, 0, stream>>>(
            S, mj, invD, XTh, XTl, Xh, Xl, F1h, F1l, Yh, Yl);
        // fused: f[step] rowsum of Y + P_{step+1} = Y @ Ww + b (skip P on last)
        if (step < L_ - 1) {
            k_mf_pw<1><<<dim3(2, 256), 256, 0, stream>>>(
                Yh, Yl, WwTh, WwTl, WgTh, WgTl, Ww_b, Wg_b, Ph, Pl, f, step);
            k_transpose_bf2<<<dim3(4, 8, 128), 256, 0, stream>>>(Yh, Yl, XTh, XTl);
        } else {
            k_mf_pw<0><<<dim3(2, 256), 256, 0, stream>>>(
                Yh, Yl, WwTh, WwTl, WgTh, WgTl, Ww_b, Wg_b, Ph, Pl, f, step);
        }
        const u16 *nxh = Yh, *nxl = Yl;
        if (step == 1) { Yh = X2h; Yl = X2l; }
        else           { Yh = (u16*)Xh; Yl = (u16*)Xl; }
        Xh = nxh; Xl = nxl;
    }

    k_rownorm<<<B_, 256, 0, stream>>>(f);

    // --- MLP head (fp32 split-K): 1536 -> 1536 -> 768 -> 128 ---
    const dim3 fblk(16, 16);
    k_gemm_splitk<<<dim3(24, 1, 16), fblk, 0, stream>>>(f,  W0, Part, B_, HID_, HID_, 96);
    k_reduce_bias_act<1><<<384, 256, 0, stream>>>(Part, b0, h0, B_ * HID_, HID_, 16);
    k_gemm_splitk<<<dim3(24, 1, 16), fblk, 0, stream>>>(h0, W1, Part, B_, HID_, HID_, 96);
    k_reduce_bias_act<1><<<384, 256, 0, stream>>>(Part, b1, h1, B_ * HID_, HID_, 16);
    k_gemm_splitk<<<dim3(12, 1, 16), fblk, 0, stream>>>(h1, W2, Part, B_, 768, HID_, 96);
    k_reduce_bias_act<1><<<192, 256, 0, stream>>>(Part, b2, h2, B_ * 768, 768, 16);
    k_gemm_splitk<<<dim3(2, 1, 8),   fblk, 0, stream>>>(h2, W3, Part, B_, 128, 768, 96);
    k_reduce_bias_act<0><<<32, 256, 0, stream>>>(Part, b3, out, B_ * 128, 128, 8);
}

// Round 12
// 851.146 us; speedup vs baseline: 3.2898x; 1.1493x over previous
//
#include <hip/hip_runtime.h>

#define B_   64
#define N_   512
#define R_   256
#define L_   6
#define HID_ 1536

#define BM 128
#define BN 128
#define BK 32
#define LDT 40   // padded LDS stride (u16 elems); 2-way bank alias only = free
#define TLD 72   // transpose tile stride

typedef __attribute__((ext_vector_type(4))) float f32x4;
typedef __attribute__((ext_vector_type(8))) __bf16 bf16x8;
typedef __attribute__((ext_vector_type(8))) unsigned short u16x8;
typedef unsigned short u16;
typedef unsigned char  u8;
typedef unsigned int   u32;

__device__ __forceinline__ float silu_f(float x) { return x / (1.0f + __expf(-x)); }

__device__ __forceinline__ float bf2f(u16 h) {
    u32 u = ((u32)h) << 16;
    return __builtin_bit_cast(float, u);
}
// truncation split: x ~= hi + lo with ~17 effective mantissa bits
__device__ __forceinline__ void split2(float x, u16& h, u16& l) {
    u32 u = __builtin_bit_cast(u32, x);
    h = (u16)(u >> 16);
    float r = x - __builtin_bit_cast(float, u & 0xffff0000u);   // exact
    l = (u16)(__builtin_bit_cast(u32, r) >> 16);
}
__device__ __forceinline__ float join2(u16 h, u16 l) {
    return bf2f(h) + bf2f(l);
}

// ===========================================================================
// Split-GEMM core helper: ACC += Ah*Bh + Al*Bh + Ah*Bl
// ===========================================================================
#define MFMA_TRIPLE(ACC, Ash, Asl, Bsh, Bsl)                                    \
    {                                                                           \
        const int k8 = (lane >> 4) * 8, cl = lane & 15;                         \
        bf16x8 bh[4], bl[4];                                                    \
        _Pragma("unroll")                                                       \
        for (int n = 0; n < 4; ++n) {                                           \
            bh[n] = *(const bf16x8*)&Bsh[(wc * 64 + n * 16 + cl) * LDT + k8];   \
            bl[n] = *(const bf16x8*)&Bsl[(wc * 64 + n * 16 + cl) * LDT + k8];   \
        }                                                                       \
        _Pragma("unroll")                                                       \
        for (int m = 0; m < 4; ++m) {                                           \
            bf16x8 ah = *(const bf16x8*)&Ash[(wr * 64 + m * 16 + cl) * LDT + k8]; \
            bf16x8 al = *(const bf16x8*)&Asl[(wr * 64 + m * 16 + cl) * LDT + k8]; \
            _Pragma("unroll")                                                   \
            for (int n = 0; n < 4; ++n) {                                       \
                ACC[m][n] = __builtin_amdgcn_mfma_f32_16x16x32_bf16(ah, bh[n], ACC[m][n], 0, 0, 0); \
                ACC[m][n] = __builtin_amdgcn_mfma_f32_16x16x32_bf16(al, bh[n], ACC[m][n], 0, 0, 0); \
                ACC[m][n] = __builtin_amdgcn_mfma_f32_16x16x32_bf16(ah, bl[n], ACC[m][n], 0, 0, 0); \
            }                                                                   \
        }                                                                       \
    }

#define STAGE2(DSTH, DSTL, SRCH, SRCL)                                          \
    {                                                                           \
        *(u16x8*)&DSTH[sr * LDT + sc]     = *(const u16x8*)(SRCH);              \
        *(u16x8*)&DSTH[sr * LDT + sc + 8] = *(const u16x8*)(SRCH + 8);          \
        *(u16x8*)&DSTL[sr * LDT + sc]     = *(const u16x8*)(SRCL);              \
        *(u16x8*)&DSTL[sr * LDT + sc + 8] = *(const u16x8*)(SRCL + 8);          \
    }

#define ZERO_ACC(ACC)                                                           \
    _Pragma("unroll")                                                           \
    for (int m = 0; m < 4; ++m)                                                 \
        _Pragma("unroll")                                                       \
        for (int n = 0; n < 4; ++n)                                             \
            ACC[m][n] = (f32x4){0.0f, 0.0f, 0.0f, 0.0f};

// ===========================================================================
// C = act(A @ W + bias), A: fp32 (AFP32=1, on-the-fly split) or hi/lo pair.
// ===========================================================================
template<int ACT, int AFP32>
__global__ __launch_bounds__(256)
void k_mf_gemm(const float* __restrict__ Af,
               const u16* __restrict__ Ah, const u16* __restrict__ Al,
               const u16* __restrict__ WTh, const u16* __restrict__ WTl,
               const float* __restrict__ bias,
               u16* __restrict__ Ch, u16* __restrict__ Cl,
               int M, int Nn, int K)
{
    __shared__ u16 Ash[BM * LDT], Asl[BM * LDT];
    __shared__ u16 Bsh[BN * LDT], Bsl[BN * LDT];
    const int t = threadIdx.x, lane = t & 63, w = t >> 6;
    const int wr = w >> 1, wc = w & 1;
    const int m0 = blockIdx.y * BM, n0 = blockIdx.x * BN;
    const int sr = t >> 1, sc = (t & 1) * 16;
    f32x4 acc[4][4] = {};
    for (int k0 = 0; k0 < K; k0 += BK) {
        if (AFP32) {
            const float* ga = Af + (size_t)(m0 + sr) * K + k0 + sc;
            u16x8 vh0, vl0, vh1, vl1;
            #pragma unroll
            for (int p = 0; p < 2; ++p) {
                const float4 a = *(const float4*)(ga + p * 8);
                const float4 b = *(const float4*)(ga + p * 8 + 4);
                u16 h, l;
                split2(a.x, h, l); (p ? vh1 : vh0)[0] = h; (p ? vl1 : vl0)[0] = l;
                split2(a.y, h, l); (p ? vh1 : vh0)[1] = h; (p ? vl1 : vl0)[1] = l;
                split2(a.z, h, l); (p ? vh1 : vh0)[2] = h; (p ? vl1 : vl0)[2] = l;
                split2(a.w, h, l); (p ? vh1 : vh0)[3] = h; (p ? vl1 : vl0)[3] = l;
                split2(b.x, h, l); (p ? vh1 : vh0)[4] = h; (p ? vl1 : vl0)[4] = l;
                split2(b.y, h, l); (p ? vh1 : vh0)[5] = h; (p ? vl1 : vl0)[5] = l;
                split2(b.z, h, l); (p ? vh1 : vh0)[6] = h; (p ? vl1 : vl0)[6] = l;
                split2(b.w, h, l); (p ? vh1 : vh0)[7] = h; (p ? vl1 : vl0)[7] = l;
            }
            *(u16x8*)&Ash[sr * LDT + sc]     = vh0;
            *(u16x8*)&Ash[sr * LDT + sc + 8] = vh1;
            *(u16x8*)&Asl[sr * LDT + sc]     = vl0;
            *(u16x8*)&Asl[sr * LDT + sc + 8] = vl1;
        } else {
            const u16* gah = Ah + (size_t)(m0 + sr) * K + k0 + sc;
            const u16* gal = Al + (size_t)(m0 + sr) * K + k0 + sc;
            STAGE2(Ash, Asl, gah, gal)
        }
        const u16* gbh = WTh + (size_t)(n0 + sr) * K + k0 + sc;
        const u16* gbl = WTl + (size_t)(n0 + sr) * K + k0 + sc;
        STAGE2(Bsh, Bsl, gbh, gbl)
        __syncthreads();
        MFMA_TRIPLE(acc, Ash, Asl, Bsh, Bsl)
        __syncthreads();
    }
    const int cl2 = lane & 15, rh = lane >> 4;
    #pragma unroll
    for (int m = 0; m < 4; ++m)
        #pragma unroll
        for (int n = 0; n < 4; ++n) {
            const int col = n0 + wc * 64 + n * 16 + cl2;
            const float bb = bias[col];
            #pragma unroll
            for (int q = 0; q < 4; ++q) {
                const int row = m0 + wr * 64 + m * 16 + rh * 4 + q;
                float v = acc[m][n][q] + bb;
                if (ACT) v = silu_f(v);
                const size_t idx = (size_t)row * Nn + col;
                split2(v, Ch[idx], Cl[idx]);
            }
        }
}

// ===========================================================================
// Union kernel: blocks [0,512) = phase-split {P = X@Ww + bw (DO_P); f rowsum
// of silu(X@Wg + bg)}; blocks [512, 4608) = transpose X -> XT (DO_P only).
// Phase split keeps LDS at 40KB and one live acc -> 4 blocks/CU, 4 waves/SIMD.
// ===========================================================================
template<int DO_P>
__global__ __launch_bounds__(256)
void k_pwt(const u16* __restrict__ Xh, const u16* __restrict__ Xl,
           const u16* __restrict__ WwTh, const u16* __restrict__ WwTl,
           const u16* __restrict__ WgTh, const u16* __restrict__ WgTl,
           const float* __restrict__ bw, const float* __restrict__ bg,
           u16* __restrict__ Ph, u16* __restrict__ Pl,
           u16* __restrict__ XTh, u16* __restrict__ XTl,
           float* __restrict__ f, int step)
{
    __shared__ u16 smem[4 * BM * LDT];
    const int gid = blockIdx.x;
    const int t = threadIdx.x;

    if (gid >= 512) {
        // ---- transpose part (reads X only; no hazard with pw part) ----
        const int tid = gid - 512;
        const int xq = tid & 3, yq = (tid >> 2) & 7, zz = tid >> 5;
        const int pl = zz & 1, b = zz >> 1;
        const u16* Fn = pl ? Xl : Xh;
        u16*       FT = pl ? XTl : XTh;
        const int i0 = yq * 64, r0 = xq * 64;
        u16* tile = smem;
        const u16* src = Fn + ((size_t)b * N_ + i0) * R_ + r0;
        u16*       dst = FT + ((size_t)b * R_ + r0) * N_ + i0;
        const int rr = t >> 2, cc = (t & 3) * 16;
        *(u16x8*)&tile[rr * TLD + cc]     = *(const u16x8*)(src + (size_t)rr * R_ + cc);
        *(u16x8*)&tile[rr * TLD + cc + 8] = *(const u16x8*)(src + (size_t)rr * R_ + cc + 8);
        __syncthreads();
        u16x8 v0, v1;
        #pragma unroll
        for (int q = 0; q < 8; ++q) v0[q] = tile[(cc + q) * TLD + rr];
        #pragma unroll
        for (int q = 0; q < 8; ++q) v1[q] = tile[(cc + 8 + q) * TLD + rr];
        *(u16x8*)(dst + (size_t)rr * N_ + cc)     = v0;
        *(u16x8*)(dst + (size_t)rr * N_ + cc + 8) = v1;
        return;
    }

    // ---- pw part ----
    const int lane = t & 63, w = t >> 6;
    const int wr = w >> 1, wc = w & 1;
    const int m0 = (gid >> 1) * BM, n0 = (gid & 1) * BN;
    const int sr = t >> 1, sc = (t & 1) * 16;
    u16* Ash = smem;
    u16* Asl = smem + BM * LDT;
    u16* Bsh = smem + 2 * BM * LDT;
    u16* Bsl = smem + 3 * BM * LDT;
    const int cl2 = lane & 15, rh = lane >> 4;
    f32x4 acc[4][4];

    if (DO_P) {
        ZERO_ACC(acc)
        for (int k0 = 0; k0 < R_; k0 += BK) {
            const u16* gah = Xh + (size_t)(m0 + sr) * R_ + k0 + sc;
            const u16* gal = Xl + (size_t)(m0 + sr) * R_ + k0 + sc;
            STAGE2(Ash, Asl, gah, gal)
            const u16* gwh = WwTh + (size_t)(n0 + sr) * R_ + k0 + sc;
            const u16* gwl = WwTl + (size_t)(n0 + sr) * R_ + k0 + sc;
            STAGE2(Bsh, Bsl, gwh, gwl)
            __syncthreads();
            MFMA_TRIPLE(acc, Ash, Asl, Bsh, Bsl)
            __syncthreads();
        }
        #pragma unroll
        for (int m = 0; m < 4; ++m)
            #pragma unroll
            for (int n = 0; n < 4; ++n) {
                const int col = n0 + wc * 64 + n * 16 + cl2;
                const float bwv = bw[col];
                #pragma unroll
                for (int q = 0; q < 4; ++q) {
                    const int row = m0 + wr * 64 + m * 16 + rh * 4 + q;
                    const size_t idx = (size_t)row * R_ + col;
                    split2(acc[m][n][q] + bwv, Ph[idx], Pl[idx]);
                }
            }
    }

    // phase G (reuses acc and LDS; last barrier of phase P protects staging)
    ZERO_ACC(acc)
    for (int k0 = 0; k0 < R_; k0 += BK) {
        const u16* gah = Xh + (size_t)(m0 + sr) * R_ + k0 + sc;
        const u16* gal = Xl + (size_t)(m0 + sr) * R_ + k0 + sc;
        STAGE2(Ash, Asl, gah, gal)
        const u16* ggh = WgTh + (size_t)(n0 + sr) * R_ + k0 + sc;
        const u16* ggl = WgTl + (size_t)(n0 + sr) * R_ + k0 + sc;
        STAGE2(Bsh, Bsl, ggh, ggl)
        __syncthreads();
        MFMA_TRIPLE(acc, Ash, Asl, Bsh, Bsl)
        __syncthreads();
    }
    const int bb = gid >> 3;                     // (gid>>1)>>2: batch of m-block
    #pragma unroll
    for (int n = 0; n < 4; ++n) {
        const int col = n0 + wc * 64 + n * 16 + cl2;
        const float bias = bg[col];
        float s = 0.0f;
        #pragma unroll
        for (int m = 0; m < 4; ++m)
            #pragma unroll
            for (int q = 0; q < 4; ++q)
                s += silu_f(acc[m][n][q] + bias);
        s += __shfl_xor(s, 16);
        s += __shfl_xor(s, 32);
        if (rh == 0)
            atomicAdd(&f[(size_t)bb * HID_ + step * R_ + col], s);
    }
}

// ===========================================================================
// S[b,i,j] = sum_r P[b,i,r]*Fn[b,j,r], masked -> fp32, PLUS per-tile column
// stats (max, sumexp over this block's 128 rows) -> pm/ps partials.
// Grid (64 b, 4 j-tiles, 4 i-tiles): same-b blocks ≡ b (mod 8) -> same XCD L2
// ===========================================================================
__global__ __launch_bounds__(256)
void k_mf_abt(const u16* __restrict__ Ph, const u16* __restrict__ Pl,
              const u16* __restrict__ Fh, const u16* __restrict__ Fl,
              const u8* __restrict__ msk, float* __restrict__ S,
              float* __restrict__ pm, float* __restrict__ ps)
{
    __shared__ u16 Ash[BM * LDT], Asl[BM * LDT];
    __shared__ u16 Bsh[BN * LDT], Bsl[BN * LDT];
    const int t = threadIdx.x, lane = t & 63, w = t >> 6;
    const int wr = w >> 1, wc = w & 1;
    const int b = blockIdx.x;
    const int j0 = blockIdx.y * BN, i0 = blockIdx.z * BM;
    const size_t boff = (size_t)b * N_ * R_;
    const int sr = t >> 1, sc = (t & 1) * 16;
    f32x4 acc[4][4] = {};
    for (int k0 = 0; k0 < R_; k0 += BK) {
        const u16* gah = Ph + boff + (size_t)(i0 + sr) * R_ + k0 + sc;
        const u16* gal = Pl + boff + (size_t)(i0 + sr) * R_ + k0 + sc;
        STAGE2(Ash, Asl, gah, gal)
        const u16* gbh = Fh + boff + (size_t)(j0 + sr) * R_ + k0 + sc;
        const u16* gbl = Fl + boff + (size_t)(j0 + sr) * R_ + k0 + sc;
        STAGE2(Bsh, Bsl, gbh, gbl)
        __syncthreads();
        MFMA_TRIPLE(acc, Ash, Asl, Bsh, Bsl)
        __syncthreads();
    }
    const int cl2 = lane & 15, rh = lane >> 4;
    const u8*   mb = msk + (size_t)b * N_ * N_;
    float*      Sb = S   + (size_t)b * N_ * N_;
    // stats scratch aliases Ash (safe: all MFMA reads completed at last barrier)
    float* smax = (float*)Ash;         // [8][128]
    float* ssum = smax + 1024;         // [8][128]
    const int slot = wr * 4 + rh;
    #pragma unroll
    for (int n = 0; n < 4; ++n) {
        const int col = wc * 64 + n * 16 + cl2;       // local col in tile
        u32 mbits = 0;
        float lm = -3.0e38f;
        #pragma unroll
        for (int m = 0; m < 4; ++m)
            #pragma unroll
            for (int q = 0; q < 4; ++q) {
                const int row = i0 + wr * 64 + m * 16 + rh * 4 + q;
                const size_t idx = (size_t)row * N_ + (j0 + col);
                const u32 on = mb[idx] ? 1u : 0u;
                const float v = on ? acc[m][n][q] : -1.0e8f;
                Sb[idx] = v;
                mbits |= on << (m * 4 + q);
                lm = fmaxf(lm, v);
            }
        float ls = 0.0f;
        #pragma unroll
        for (int m = 0; m < 4; ++m)
            #pragma unroll
            for (int q = 0; q < 4; ++q) {
                const float v = ((mbits >> (m * 4 + q)) & 1u) ? acc[m][n][q] : -1.0e8f;
                ls += __expf(v - lm);
            }
        smax[slot * 128 + col] = lm;
        ssum[slot * 128 + col] = ls;
    }
    __syncthreads();
    if (t < 128) {
        float M = smax[t];
        #pragma unroll
        for (int s2 = 1; s2 < 8; ++s2) M = fmaxf(M, smax[s2 * 128 + t]);
        float D = 0.0f;
        #pragma unroll
        for (int s2 = 0; s2 < 8; ++s2) D += ssum[s2 * 128 + t] * __expf(smax[s2 * 128 + t] - M);
        const size_t o = ((size_t)(b * 4 + blockIdx.z) * 512) + j0 + t;
        pm[o] = M; ps[o] = D;
    }
}

// ===========================================================================
// Combine 4 i-tile partials per column -> mj, invD (1MB traffic total)
// ===========================================================================
__global__ __launch_bounds__(256)
void k_stats_combine(const float* __restrict__ pm, const float* __restrict__ ps,
                     float* __restrict__ mj, float* __restrict__ invD)
{
    const int idx = blockIdx.x * 256 + threadIdx.x;   // b*512 + j, 0..32767
    const int b = idx >> 9, j = idx & 511;
    const size_t base = (size_t)(b * 4) * 512 + j;
    float M = pm[base];
    #pragma unroll
    for (int k = 1; k < 4; ++k) M = fmaxf(M, pm[base + (size_t)k * 512]);
    float D = 0.0f;
    #pragma unroll
    for (int k = 0; k < 4; ++k) D += ps[base + (size_t)k * 512] * __expf(pm[base + (size_t)k * 512] - M);
    mj[idx]   = M;
    invD[idx] = 1.0f / D;
}

// ===========================================================================
// Out = (Fn + softmax(S) @ Fn) * F1 ; A staged from fp32 S (exp-normalized,
// split hi/lo), B = FT hi/lo; output split hi/lo
// ===========================================================================
__global__ __launch_bounds__(256)
void k_mf_af(const float* __restrict__ S, const float* __restrict__ mj,
             const float* __restrict__ invD,
             const u16* __restrict__ FTh, const u16* __restrict__ FTl,
             const u16* __restrict__ Fh, const u16* __restrict__ Fl,
             const u16* __restrict__ F1h, const u16* __restrict__ F1l,
             u16* __restrict__ Oh, u16* __restrict__ Ol)
{
    __shared__ u16 Ash[BM * LDT], Asl[BM * LDT];
    __shared__ u16 Bsh[BN * LDT], Bsl[BN * LDT];
    const int t = threadIdx.x, lane = t & 63, w = t >> 6;
    const int wr = w >> 1, wc = w & 1;
    const int b = blockIdx.x;
    const int r0 = blockIdx.y * BN, i0 = blockIdx.z * BM;
    const float* Sb  = S    + (size_t)b * N_ * N_;
    const float* mb  = mj   + (size_t)b * N_;
    const float* db  = invD + (size_t)b * N_;
    const size_t tboff = (size_t)b * R_ * N_;
    const int sr = t >> 1, sc = (t & 1) * 16;
    f32x4 acc[4][4] = {};
    for (int k0 = 0; k0 < N_; k0 += BK) {          // k = j
        const float* gs = Sb + (size_t)(i0 + sr) * N_ + k0 + sc;
        const float* gm = mb + k0 + sc;
        const float* gd = db + k0 + sc;
        #pragma unroll
        for (int h = 0; h < 2; ++h) {
            u16x8 vh, vl;
            #pragma unroll
            for (int p4 = 0; p4 < 2; ++p4) {
                const float4 sv = *(const float4*)(gs + h * 8 + p4 * 4);
                const float4 mv = *(const float4*)(gm + h * 8 + p4 * 4);
                const float4 dv = *(const float4*)(gd + h * 8 + p4 * 4);
                u16 th, tl;
                split2(__expf(sv.x - mv.x) * dv.x, th, tl); vh[p4 * 4 + 0] = th; vl[p4 * 4 + 0] = tl;
                split2(__expf(sv.y - mv.y) * dv.y, th, tl); vh[p4 * 4 + 1] = th; vl[p4 * 4 + 1] = tl;
                split2(__expf(sv.z - mv.z) * dv.z, th, tl); vh[p4 * 4 + 2] = th; vl[p4 * 4 + 2] = tl;
                split2(__expf(sv.w - mv.w) * dv.w, th, tl); vh[p4 * 4 + 3] = th; vl[p4 * 4 + 3] = tl;
            }
            *(u16x8*)&Ash[sr * LDT + sc + h * 8] = vh;
            *(u16x8*)&Asl[sr * LDT + sc + h * 8] = vl;
        }
        const u16* gbh = FTh + tboff + (size_t)(r0 + sr) * N_ + k0 + sc;
        const u16* gbl = FTl + tboff + (size_t)(r0 + sr) * N_ + k0 + sc;
        STAGE2(Bsh, Bsl, gbh, gbl)
        __syncthreads();
        MFMA_TRIPLE(acc, Ash, Asl, Bsh, Bsl)
        __syncthreads();
    }
    const int cl2 = lane & 15, rh = lane >> 4;
    #pragma unroll
    for (int m = 0; m < 4; ++m)
        #pragma unroll
        for (int n = 0; n < 4; ++n)
            #pragma unroll
            for (int q = 0; q < 4; ++q) {
                const int row = i0 + wr * 64 + m * 16 + rh * 4 + q;
                const int col = r0 + wc * 64 + n * 16 + cl2;
                const size_t idx = ((size_t)b * N_ + row) * R_ + col;
                const float fn = join2(Fh[idx], Fl[idx]);
                const float f1 = join2(F1h[idx], F1l[idx]);
                split2((fn + acc[m][n][q]) * f1, Oh[idx], Ol[idx]);
            }
}

// WT[n,k] hi/lo = split(W[k,n])
__global__ __launch_bounds__(256)
void k_cvt_wT(const float* __restrict__ Win, u16* __restrict__ WTh,
              u16* __restrict__ WTl, int K, int Nn)
{
    const int idx = blockIdx.x * 256 + threadIdx.x;
    if (idx < K * Nn) {
        const int n = idx / K, k = idx % K;
        split2(Win[(size_t)k * Nn + n], WTh[idx], WTl[idx]);
    }
}

// adj int32 -> u8 mask (4 elems/thread)
__global__ __launch_bounds__(256)
void k_adj_mask(const int* __restrict__ adj, u8* __restrict__ msk, int n4)
{
    const int i = blockIdx.x * 256 + threadIdx.x;
    if (i < n4) {
        const int4 a = *(const int4*)(adj + (size_t)i * 4);
        uchar4 m;
        m.x = a.x ? 1 : 0; m.y = a.y ? 1 : 0;
        m.z = a.z ? 1 : 0; m.w = a.w ? 1 : 0;
        *(uchar4*)(msk + (size_t)i * 4) = m;
    }
}

// ===========================================================================
// Split-K fp32 GEMM + reduce for the thin MLP head (M=64)
// ===========================================================================
#define TS 64
#define FBK 16
__global__ __launch_bounds__(256)
void k_gemm_splitk(const float* __restrict__ A, const float* __restrict__ W,
                   float* __restrict__ Part, int M, int Nn, int K, int klen)
{
    __shared__ float As[FBK][TS];
    __shared__ float Ws[FBK][TS];
    const int tx = threadIdx.x, ty = threadIdx.y;
    const int t  = ty * 16 + tx;
    const int n0 = blockIdx.x * TS;
    const int kb = blockIdx.z * klen;
    const int alm = t >> 2, alk = (t & 3) * 4;
    const int wr  = t >> 4, wc  = (t & 15) * 4;
    float acc[4][4] = {};
    for (int k0 = kb; k0 < kb + klen; k0 += FBK) {
        float4 av = *(const float4*)(A + (size_t)alm * K + k0 + alk);
        As[alk + 0][alm] = av.x; As[alk + 1][alm] = av.y;
        As[alk + 2][alm] = av.z; As[alk + 3][alm] = av.w;
        *(float4*)(&Ws[wr][wc]) = *(const float4*)(W + (size_t)(k0 + wr) * Nn + n0 + wc);
        __syncthreads();
        #pragma unroll
        for (int k = 0; k < FBK; ++k) {
            float a[4], w2[4];
            #pragma unroll
            for (int q = 0; q < 4; ++q) { a[q] = As[k][ty * 4 + q]; w2[q] = Ws[k][tx * 4 + q]; }
            #pragma unroll
            for (int ii = 0; ii < 4; ++ii)
                #pragma unroll
                for (int jj = 0; jj < 4; ++jj)
                    acc[ii][jj] = fmaf(a[ii], w2[jj], acc[ii][jj]);
        }
        __syncthreads();
    }
    float* Pb = Part + (size_t)blockIdx.z * M * Nn;
    #pragma unroll
    for (int ii = 0; ii < 4; ++ii) {
        const int m = ty * 4 + ii;
        #pragma unroll
        for (int jj = 0; jj < 4; ++jj)
            Pb[(size_t)m * Nn + n0 + tx * 4 + jj] = acc[ii][jj];
    }
}

template<int ACT>
__global__ __launch_bounds__(256)
void k_reduce_bias_act(const float* __restrict__ Part, const float* __restrict__ bias,
                       float* __restrict__ C, int MN, int Nn, int SK)
{
    const int i = blockIdx.x * 256 + threadIdx.x;
    if (i < MN) {
        float s = 0.0f;
        for (int k = 0; k < SK; ++k) s += Part[(size_t)k * MN + i];
        float v = s + bias[i % Nn];
        if (ACT) v = silu_f(v);
        C[i] = v;
    }
}

__global__ __launch_bounds__(256)
void k_rownorm(float* __restrict__ f)
{
    __shared__ float red[256];
    const int b = blockIdx.x, t = threadIdx.x;
    float ss = 0.0f;
    for (int c = t; c < HID_; c += 256) {
        const float v = f[(size_t)b * HID_ + c];
        ss += v * v;
    }
    red[t] = ss;
    __syncthreads();
    for (int o = 128; o > 0; o >>= 1) {
        if (t < o) red[t] += red[t + o];
        __syncthreads();
    }
    const float inv = 1.0f / fmaxf(sqrtf(red[0]), 1e-12f);
    for (int c = t; c < HID_; c += 256)
        f[(size_t)b * HID_ + c] *= inv;
}

// ===========================================================================
extern "C" void kernel_launch(void* const* d_in, const int* in_sizes, int n_in,
                              void* d_out, int out_size, void* d_ws, size_t ws_size,
                              hipStream_t stream)
{
    const float* node = (const float*)d_in[0];
    const int*   adj  = (const int*)d_in[1];
    const float* Wv_w = (const float*)d_in[3];  const float* Wv_b = (const float*)d_in[4];
    const float* Ww_w = (const float*)d_in[5];  const float* Ww_b = (const float*)d_in[6];
    const float* Wg_w = (const float*)d_in[7];  const float* Wg_b = (const float*)d_in[8];
    const float* W0 = (const float*)d_in[9];    const float* b0 = (const float*)d_in[10];
    const float* W1 = (const float*)d_in[11];   const float* b1 = (const float*)d_in[12];
    const float* W2 = (const float*)d_in[13];   const float* b2 = (const float*)d_in[14];
    const float* W3 = (const float*)d_in[15];   const float* b3 = (const float*)d_in[16];
    float* out = (float*)d_out;

    float* ws = (float*)d_ws;
    const size_t SZ = (size_t)B_ * N_ * R_;              // 8,388,608 elems
    float* S     = ws;                                   // B*N*N fp32 (walk loop)
    float* h0    = ws;                                   // alias S (post-loop)
    float* h1    = ws + 98304;
    float* h2    = ws + 196608;
    float* Part  = ws + 262144;                          // 16*98304 floats (in S region)
    float* mj    = ws + (size_t)B_ * N_ * N_;            // 32768
    float* invD  = mj + 32768;
    float* f     = invD + 32768;                         // 98304
    float* pm    = f + 98304;                            // 131072 (64*4*512)
    float* ps    = pm + 131072;                          // 131072
    u16* u0   = (u16*)(ps + 131072);
    u16* F1h  = u0;            u16* F1l  = F1h + SZ;
    u16* X1h  = F1l + SZ;      u16* X1l  = X1h + SZ;
    u16* X2h  = X1l + SZ;      u16* X2l  = X2h + SZ;
    u16* XTh  = X2l + SZ;      u16* XTl  = XTh + SZ;
    u16* Ph   = XTl + SZ;      u16* Pl   = Ph + SZ;
    u16* WvTh = Pl + SZ;       u16* WvTl = WvTh + 65536;
    u16* WwTh = WvTl + 65536;  u16* WwTl = WwTh + 65536;
    u16* WgTh = WwTl + 65536;  u16* WgTl = WgTh + 65536;
    u8*  msk  = (u8*)(WgTl + 65536);

    // --- one-time conversions ---
    k_cvt_wT<<<256, 256, 0, stream>>>(Wv_w, WvTh, WvTl, 256, 256);
    k_cvt_wT<<<256, 256, 0, stream>>>(Ww_w, WwTh, WwTl, 256, 256);
    k_cvt_wT<<<256, 256, 0, stream>>>(Wg_w, WgTh, WgTl, 256, 256);
    k_adj_mask<<<16384, 256, 0, stream>>>(adj, msk, B_ * N_ * N_ / 4);
    (void)hipMemsetAsync(f, 0, 98304 * sizeof(float), stream);

    // --- F1 = silu(node @ Wv + b)  (A = fp32 node, on-the-fly split) ---
    k_mf_gemm<1, 1><<<dim3(2, 256), 256, 0, stream>>>(
        node, nullptr, nullptr, WvTh, WvTl, Wv_b, F1h, F1l, B_ * N_, R_, 256);
    // fused: P_1 = F1@Ww + b, f[0] rowsum, F1 -> XT transpose
    k_pwt<1><<<4608, 256, 0, stream>>>(
        F1h, F1l, WwTh, WwTl, WgTh, WgTl, Ww_b, Wg_b, Ph, Pl, XTh, XTl, f, 0);

    const u16 *Xh = F1h, *Xl = F1l;
    u16 *Yh = X1h, *Yl = X1l;
    for (int step = 1; step < L_; ++step) {
        k_mf_abt<<<dim3(64, 4, 4), 256, 0, stream>>>(Ph, Pl, Xh, Xl, msk, S, pm, ps);
        k_stats_combine<<<128, 256, 0, stream>>>(pm, ps, mj, invD);
        k_mf_af<<<dim3(64, 2, 4), 256, 0, stream>>>(
            S, mj, invD, XTh, XTl, Xh, Xl, F1h, F1l, Yh, Yl);
        if (step < L_ - 1) {
            k_pwt<1><<<4608, 256, 0, stream>>>(
                Yh, Yl, WwTh, WwTl, WgTh, WgTl, Ww_b, Wg_b, Ph, Pl, XTh, XTl, f, step);
        } else {
            k_pwt<0><<<512, 256, 0, stream>>>(
                Yh, Yl, WwTh, WwTl, WgTh, WgTl, Ww_b, Wg_b, Ph, Pl, XTh, XTl, f, step);
        }
        const u16 *nxh = Yh, *nxl = Yl;
        if (step == 1) { Yh = X2h; Yl = X2l; }
        else           { Yh = (u16*)Xh; Yl = (u16*)Xl; }
        Xh = nxh; Xl = nxl;
    }

    k_rownorm<<<B_, 256, 0, stream>>>(f);

    // --- MLP head (fp32 split-K): 1536 -> 1536 -> 768 -> 128 ---
    const dim3 fblk(16, 16);
    k_gemm_splitk<<<dim3(24, 1, 16), fblk, 0, stream>>>(f,  W0, Part, B_, HID_, HID_, 96);
    k_reduce_bias_act<1><<<384, 256, 0, stream>>>(Part, b0, h0, B_ * HID_, HID_, 16);
    k_gemm_splitk<<<dim3(24, 1, 16), fblk, 0, stream>>>(h0, W1, Part, B_, HID_, HID_, 96);
    k_reduce_bias_act<1><<<384, 256, 0, stream>>>(Part, b1, h1, B_ * HID_, HID_, 16);
    k_gemm_splitk<<<dim3(12, 1, 16), fblk, 0, stream>>>(h1, W2, Part, B_, 768, HID_, 96);
    k_reduce_bias_act<1><<<192, 256, 0, stream>>>(Part, b2, h2, B_ * 768, 768, 16);
    k_gemm_splitk<<<dim3(2, 1, 8),   fblk, 0, stream>>>(h2, W3, Part, B_, 128, 768, 96);
    k_reduce_bias_act<0><<<32, 256, 0, stream>>>(Part, b3, out, B_ * 128, 128, 8);
}